// Round 1
// baseline (1706.582 us; speedup 1.0000x reference)
//
#include <hip/hip_runtime.h>
#include <stdint.h>

typedef __attribute__((ext_vector_type(8))) short short8;
typedef __attribute__((ext_vector_type(4))) float f32x4;

#define D_ 64
#define NODE_DIM_ 6
#define INF_ 204      // IN_FEAT = 3*64 + 2*6
#define KPAD 232      // padded K per edge row in bf16 elems (>= 7*32=224; 464B row -> conflict-free b128)
#define NR_STRIDE 72  // node_rep row stride in f32 (70 used + 2 pad)
#define EB 32         // edges per GEMM block
#define WP_PER_LAYER 14336  // 4*7*64*8 bf16 elements

__device__ __forceinline__ short f2bf(float f){
  uint32_t u = __float_as_uint(f);
  u += 0x7fffu + ((u >> 16) & 1u);   // round-to-nearest-even (finite values only)
  return (short)(u >> 16);
}

__global__ void k_count_batch(const int* __restrict__ batch, int* __restrict__ counts, int n){
  int i = blockIdx.x*256 + threadIdx.x;
  if (i < n) atomicAdd(&counts[batch[i]], 1);
}

// exclusive prefix sum of counts -> head indices (B <= 1024)
__global__ void k_scan_heads(const int* __restrict__ counts, int* __restrict__ head, int B){
  __shared__ int s[1024];
  int t = threadIdx.x;
  int v = (t < B) ? counts[t] : 0;
  s[t] = v;
  __syncthreads();
  for (int off = 1; off < 1024; off <<= 1){
    int u = (t >= off) ? s[t-off] : 0;
    __syncthreads();
    s[t] += u;
    __syncthreads();
  }
  if (t < B) head[t] = s[t] - v;
}

__global__ void k_cnt_edges(const int* __restrict__ col, const float* __restrict__ mask,
                            float* __restrict__ cnt, int E){
  int e = blockIdx.x*256 + threadIdx.x;
  if (e < E) atomicAdd(&cnt[col[e]], mask[e]);
}

__global__ void k_inv(const float* __restrict__ cnt, float* __restrict__ inv, int n){
  int i = blockIdx.x*256 + threadIdx.x;
  if (i < n) inv[i] = 1.0f/(cnt[i] + 1.0f);
}

// write x0 (head/tail rows of x) into node_rep cols 64..69
__global__ void k_x0(const int* __restrict__ head, const float* __restrict__ x,
                     float* __restrict__ nrep, int B){
  int idx = blockIdx.x*256 + threadIdx.x;
  if (idx >= B*2*NODE_DIM_) return;
  int g = idx / (2*NODE_DIM_);
  int j = idx % (2*NODE_DIM_);
  int node = head[g] + j / NODE_DIM_;
  int c = j % NODE_DIM_;
  nrep[(size_t)node*NR_STRIDE + D_ + c] = x[node*NODE_DIM_ + c];
}

// pack W[l] (64x204 f32) into per-lane MFMA B-fragment order, bf16, zero-padded to K=224
__global__ void k_pack_w(const float* __restrict__ W0, const float* __restrict__ W1,
                         const float* __restrict__ W2, short* __restrict__ Wp){
  int idx = blockIdx.x*256 + threadIdx.x;
  if (idx >= 3*WP_PER_LAYER) return;
  int l = idx / WP_PER_LAYER;
  int rem = idx % WP_PER_LAYER;
  const float* W = (l==0) ? W0 : ((l==1) ? W1 : W2);
  int i    = rem & 7;
  int s    = rem >> 3;
  int lane = s & 63;
  int t    = s >> 6;       // 0..27
  int kc   = t % 7;
  int nt   = t / 7;
  int n    = lane & 15;
  int kg   = lane >> 4;
  int k    = kc*32 + kg*8 + i;
  int c    = nt*16 + n;
  float v  = (k < INF_) ? W[c*INF_ + k] : 0.f;
  Wp[idx] = f2bf(v);
}

// initial scatter: agg += edge_emb[rel[e]] * mask[e] into col[e]  (ea0 never materialized)
__global__ void k_scatter_emb(const int* __restrict__ col, const int* __restrict__ rel,
                              const float* __restrict__ emb, const float* __restrict__ mask,
                              float* __restrict__ agg, int E){
  int idx = blockIdx.x*256 + threadIdx.x;
  if (idx >= E*D_) return;
  int e = idx >> 6; int c = idx & 63;
  float v = emb[rel[e]*D_ + c];
  atomicAdd(&agg[(size_t)col[e]*D_ + c], v*mask[e]);
}

__global__ void k_nrep_update(const float* __restrict__ agg, const float* __restrict__ inv,
                              float* __restrict__ nrep, int n){
  int idx = blockIdx.x*256 + threadIdx.x;
  if (idx >= n*D_) return;
  int nn = idx >> 6; int c = idx & 63;
  nrep[(size_t)nn*NR_STRIDE + c] = agg[idx]*inv[nn];
}

__global__ void k_nrep_final(const float* __restrict__ agg, const float* __restrict__ inv,
                             float* __restrict__ out, int n){
  int idx = blockIdx.x*256 + threadIdx.x;
  if (idx >= n*D_) return;
  out[idx] = agg[idx]*inv[idx>>6];
}

// edge GEMM: ea_out[e] = relu(W @ [nrep[row],nrep[col],ea_in[e]] + b); fused agg scatter
__global__ __launch_bounds__(256) void k_gemm(
    const float* __restrict__ nrep, const float* __restrict__ ea_in,
    const int* __restrict__ rel, const float* __restrict__ emb,
    float* __restrict__ ea_out, float* __restrict__ agg,
    const int* __restrict__ eidx, const float* __restrict__ mask,
    const short* __restrict__ Wp, const float* __restrict__ bias,
    int E, int first)
{
  __shared__ __align__(16) short in_tile[EB*KPAD];
  __shared__ int   s_col[EB];
  __shared__ float s_mask[EB];
  int tid = threadIdx.x;
  int e0 = blockIdx.x*EB;
  if (tid < EB){
    int ge = e0 + tid;
    s_col[tid]  = (ge < E) ? eidx[E + ge] : 0;
    s_mask[tid] = (ge < E) ? mask[ge] : 0.f;
  }
  // stage inputs: k 0..69 = nrep[row], 70..139 = nrep[col], 140..203 = ea (or emb[rel] if first), rest 0
  for (int idx = tid; idx < EB*KPAD; idx += 256){
    int e = idx / KPAD;
    int k = idx - e*KPAD;
    int ge = e0 + e;
    float v = 0.f;
    if (ge < E){
      if (k < 70)        v = nrep[(size_t)eidx[ge]*NR_STRIDE + k];
      else if (k < 140)  v = nrep[(size_t)eidx[E+ge]*NR_STRIDE + (k-70)];
      else if (k < INF_) v = first ? emb[rel[ge]*D_ + (k-140)]
                                   : ea_in[(size_t)ge*D_ + (k-140)];
    }
    in_tile[idx] = f2bf(v);
  }
  __syncthreads();

  int lane = tid & 63, wv = tid >> 6;
  int r = lane & 15, kg = lane >> 4;
  f32x4 acc0 = {0.f,0.f,0.f,0.f}, acc1 = {0.f,0.f,0.f,0.f};
  const short8* wp = reinterpret_cast<const short8*>(Wp) + (size_t)(wv*7)*64 + lane;
  #pragma unroll
  for (int kc = 0; kc < 7; ++kc){
    short8 bw = wp[(size_t)kc*64];                       // global, L1-resident packed W
    short8 a0 = *reinterpret_cast<const short8*>(&in_tile[r*KPAD + kc*32 + kg*8]);
    short8 a1 = *reinterpret_cast<const short8*>(&in_tile[(16+r)*KPAD + kc*32 + kg*8]);
    acc0 = __builtin_amdgcn_mfma_f32_16x16x32_bf16(a0, bw, acc0, 0, 0, 0);
    acc1 = __builtin_amdgcn_mfma_f32_16x16x32_bf16(a1, bw, acc1, 0, 0, 0);
  }
  int c = wv*16 + r;
  float bc = bias[c];
  #pragma unroll
  for (int j = 0; j < 4; ++j){
    int er0 = kg*4 + j;                 // C/D: row=(lane>>4)*4+j, col=lane&15
    int ge0 = e0 + er0;
    if (ge0 < E){
      float v = acc0[j] + bc; v = v > 0.f ? v : 0.f;
      ea_out[(size_t)ge0*D_ + c] = v;
      atomicAdd(&agg[(size_t)s_col[er0]*D_ + c], v*s_mask[er0]);
    }
    int er1 = 16 + er0;
    int ge1 = e0 + er1;
    if (ge1 < E){
      float v = acc1[j] + bc; v = v > 0.f ? v : 0.f;
      ea_out[(size_t)ge1*D_ + c] = v;
      atomicAdd(&agg[(size_t)s_col[er1]*D_ + c], v*s_mask[er1]);
    }
  }
}

// graph_emb: [segment_max over graph | nrep[head] | nrep[tail]]
__global__ void k_pool(const float* __restrict__ nrep_out, const int* __restrict__ head,
                       const int* __restrict__ counts, float* __restrict__ gout, int B){
  __shared__ float s[4][64];
  int g = blockIdx.x;
  int lane = threadIdx.x & 63, sub = threadIdx.x >> 6;
  int h = head[g]; int n = counts[g];
  float m = -3.402823466e38f;
  for (int i = sub; i < n; i += 4)
    m = fmaxf(m, nrep_out[(size_t)(h+i)*D_ + lane]);
  s[sub][lane] = m;
  __syncthreads();
  if (sub == 0){
    m = fmaxf(fmaxf(s[0][lane], s[1][lane]), fmaxf(s[2][lane], s[3][lane]));
    gout[(size_t)g*192 + lane]       = m;
    gout[(size_t)g*192 + 64  + lane] = nrep_out[(size_t)h*D_ + lane];
    gout[(size_t)g*192 + 128 + lane] = nrep_out[(size_t)(h+1)*D_ + lane];
  }
}

extern "C" void kernel_launch(void* const* d_in, const int* in_sizes, int n_in,
                              void* d_out, int out_size, void* d_ws, size_t ws_size,
                              hipStream_t stream)
{
  const float* x    = (const float*)d_in[0];
  const int*   eidx = (const int*)d_in[1];
  const int*   erel = (const int*)d_in[2];
  const int*   batch= (const int*)d_in[3];
  const float* mask = (const float*)d_in[4];
  const float* emb  = (const float*)d_in[5];
  const float* W0   = (const float*)d_in[6];
  const float* b0   = (const float*)d_in[7];
  const float* W1   = (const float*)d_in[8];
  const float* b1   = (const float*)d_in[9];
  const float* W2   = (const float*)d_in[10];
  const float* b2   = (const float*)d_in[11];

  int N = in_sizes[0] / NODE_DIM_;
  int E = in_sizes[2];
  int B = (int)(((long long)out_size - (long long)N*D_ - (long long)E*D_) / 192);

  float* out_ge   = (float*)d_out;                 // B*192
  float* out_nrep = out_ge + (size_t)B*192;        // N*64
  float* out_ea   = out_nrep + (size_t)N*D_;       // E*64

  char* w = (char*)d_ws;
  auto alloc = [&](size_t bytes)->char*{ char* p = w; w += (bytes + 255) & ~(size_t)255; return p; };
  float* agg    = (float*)alloc((size_t)N*D_*4);
  float* nrep   = (float*)alloc((size_t)N*NR_STRIDE*4);
  float* cnt    = (float*)alloc((size_t)N*4);
  float* inv    = (float*)alloc((size_t)N*4);
  int*   counts = (int*)  alloc((size_t)B*4);
  int*   head   = (int*)  alloc((size_t)B*4);
  short* Wp     = (short*)alloc((size_t)3*WP_PER_LAYER*2);

  hipMemsetAsync(agg,    0, (size_t)N*D_*4, stream);
  hipMemsetAsync(nrep,   0, (size_t)N*NR_STRIDE*4, stream);
  hipMemsetAsync(cnt,    0, (size_t)N*4, stream);
  hipMemsetAsync(counts, 0, (size_t)B*4, stream);

  k_count_batch<<<(N+255)/256, 256, 0, stream>>>(batch, counts, N);
  k_scan_heads <<<1, 1024, 0, stream>>>(counts, head, B);
  k_cnt_edges  <<<(E+255)/256, 256, 0, stream>>>(eidx + E, mask, cnt, E);
  k_inv        <<<(N+255)/256, 256, 0, stream>>>(cnt, inv, N);
  k_x0         <<<(B*2*NODE_DIM_+255)/256, 256, 0, stream>>>(head, x, nrep, B);
  k_pack_w     <<<(3*WP_PER_LAYER+255)/256, 256, 0, stream>>>(W0, W1, W2, Wp);
  k_scatter_emb<<<(E*D_+255)/256, 256, 0, stream>>>(eidx + E, erel, emb, mask, agg, E);

  const float* bs[3] = {b0, b1, b2};
  int nblk = (E + EB - 1) / EB;
  for (int l = 0; l < 3; ++l){
    k_nrep_update<<<(N*D_+255)/256, 256, 0, stream>>>(agg, inv, nrep, N);
    hipMemsetAsync(agg, 0, (size_t)N*D_*4, stream);
    k_gemm<<<nblk, 256, 0, stream>>>(nrep, out_ea, erel, emb, out_ea, agg, eidx, mask,
                                     Wp + (size_t)l*WP_PER_LAYER, bs[l], E, (l==0) ? 1 : 0);
  }
  k_nrep_final<<<(N*D_+255)/256, 256, 0, stream>>>(agg, inv, out_nrep, N);
  k_pool<<<B, 256, 0, stream>>>(out_nrep, head, counts, out_ge, B);
}

// Round 2
// 1364.112 us; speedup vs baseline: 1.2511x; 1.2511x over previous
//
#include <hip/hip_runtime.h>
#include <stdint.h>

typedef __attribute__((ext_vector_type(8))) short short8;
typedef __attribute__((ext_vector_type(4))) float f32x4;
typedef __attribute__((ext_vector_type(2))) unsigned int u32x2;

#define D_ 64
#define NODE_DIM_ 6
#define INF_ 204      // IN_FEAT = 3*64 + 2*6
#define KPAD 232      // LDS row stride in bf16 elems (224 used by MFMA)
#define NR_STRIDE 72  // node_rep row stride in f32 (70 used + 2 pad; 288B, float4-aligned)
#define EB 32         // edges per GEMM block
#define OPAD 68       // epilogue f32 tile stride (272B, 16B-aligned)
#define WP_PER_LAYER 14336  // 4*7*64*8 bf16 elements

// tile k-space layout (per edge row): [0,64)=ea | [64,136)=nrep[row] (72w) | [136,208)=nrep[col] (72w) | [208,224)=0

__device__ __forceinline__ unsigned short f2bf(float f){
  uint32_t u = __float_as_uint(f);
  u += 0x7fffu + ((u >> 16) & 1u);   // RNE (finite values only)
  return (unsigned short)(u >> 16);
}

__global__ void k_count_batch(const int* __restrict__ batch, int* __restrict__ counts, int n){
  int i = blockIdx.x*256 + threadIdx.x;
  if (i < n) atomicAdd(&counts[batch[i]], 1);
}

__global__ void k_scan_heads(const int* __restrict__ counts, int* __restrict__ head, int B){
  __shared__ int s[1024];
  int t = threadIdx.x;
  int v = (t < B) ? counts[t] : 0;
  s[t] = v;
  __syncthreads();
  for (int off = 1; off < 1024; off <<= 1){
    int u = (t >= off) ? s[t-off] : 0;
    __syncthreads();
    s[t] += u;
    __syncthreads();
  }
  if (t < B) head[t] = s[t] - v;
}

// ---- CSR build (by col) ----
__global__ void k_cnt_int(const int* __restrict__ col, int* __restrict__ cnt, int E){
  int e = blockIdx.x*256 + threadIdx.x;
  if (e < E) atomicAdd(&cnt[col[e]], 1);
}

// single-block exclusive scan: off[0..N] from cnt[0..N-1]
__global__ void k_scan_off(const int* __restrict__ cnt, int* __restrict__ off, int Nn){
  __shared__ int s[1024];
  int t = threadIdx.x;
  const int CH = (Nn + 1024) / 1024;  // chunk covering N+1 writes
  int base = t*CH;
  int sum = 0;
  for (int i = 0; i < CH; ++i){ int idx = base+i; if (idx < Nn) sum += cnt[idx]; }
  s[t] = sum;
  __syncthreads();
  for (int o = 1; o < 1024; o <<= 1){
    int u = (t >= o) ? s[t-o] : 0;
    __syncthreads();
    s[t] += u;
    __syncthreads();
  }
  int run = (t == 0) ? 0 : s[t-1];
  for (int i = 0; i < CH; ++i){
    int idx = base+i;
    if (idx <= Nn){ off[idx] = run; if (idx < Nn) run += cnt[idx]; }
  }
}

__global__ void k_fill(const int* __restrict__ col, const int* __restrict__ off,
                       int* __restrict__ fpos, int* __restrict__ csr, int E){
  int e = blockIdx.x*256 + threadIdx.x;
  if (e >= E) return;
  int c = col[e];
  int p = atomicAdd(&fpos[c], 1);
  csr[off[c] + p] = e;
}

// write x0 (head/tail rows of x) into nrep cols 64..69
__global__ void k_x0(const int* __restrict__ head, const float* __restrict__ x,
                     float* __restrict__ nrep, int B){
  int idx = blockIdx.x*256 + threadIdx.x;
  if (idx >= B*2*NODE_DIM_) return;
  int g = idx / (2*NODE_DIM_);
  int j = idx % (2*NODE_DIM_);
  int node = head[g] + j / NODE_DIM_;
  int c = j % NODE_DIM_;
  nrep[(size_t)node*NR_STRIDE + D_ + c] = x[node*NODE_DIM_ + c];
}

// pack W[l] (64x204 f32) into per-lane MFMA B-fragment order (new k layout), bf16
__global__ void k_pack_w(const float* __restrict__ W0, const float* __restrict__ W1,
                         const float* __restrict__ W2, short* __restrict__ Wp){
  int idx = blockIdx.x*256 + threadIdx.x;
  if (idx >= 3*WP_PER_LAYER) return;
  int l = idx / WP_PER_LAYER;
  int rem = idx % WP_PER_LAYER;
  const float* W = (l==0) ? W0 : ((l==1) ? W1 : W2);
  int i    = rem & 7;
  int s    = rem >> 3;
  int lane = s & 63;
  int t    = s >> 6;       // 0..27 = nt*7 + kc
  int kc   = t % 7;
  int nt   = t / 7;
  int n    = lane & 15;
  int kg   = lane >> 4;
  int k    = kc*32 + kg*8 + i;   // tile k index 0..223
  int c    = nt*16 + n;          // output channel
  float v = 0.f;
  if (k < 64)       v = W[c*INF_ + 140 + k];             // ea block
  else if (k < 136){ int u = k-64;  if (u < 70) v = W[c*INF_ + u]; }       // nrep[row]
  else if (k < 208){ int u = k-136; if (u < 70) v = W[c*INF_ + 70 + u]; }  // nrep[col]
  Wp[idx] = (short)f2bf(v);
}

// gather-aggregate: nrep[n][0:64] = (sum_{e in csr(n)} src_e * mask[e]) / (sum mask + 1)
__global__ __launch_bounds__(256) void k_agg(
    const float* __restrict__ ea, const int* __restrict__ rel,
    const float* __restrict__ emb, const int* __restrict__ csr,
    const int* __restrict__ off, const float* __restrict__ mask,
    float* __restrict__ nrep, int Nn, int first)
{
  int wid = (blockIdx.x*256 + threadIdx.x) >> 6;
  if (wid >= Nn) return;
  int lane = threadIdx.x & 63;
  int s = off[wid], t = off[wid+1];
  float acc = 0.f, cs = 0.f;
  for (int i = s; i < t; ++i){
    int e = csr[i];
    float mv = mask[e];
    float v = first ? emb[rel[e]*D_ + lane] : ea[(size_t)e*D_ + lane];
    acc += v*mv; cs += mv;
  }
  nrep[(size_t)wid*NR_STRIDE + lane] = acc / (cs + 1.f);
}

__global__ __launch_bounds__(256) void k_agg_final(
    const float* __restrict__ ea, const int* __restrict__ csr,
    const int* __restrict__ off, const float* __restrict__ mask,
    float* __restrict__ out, int Nn)
{
  int wid = (blockIdx.x*256 + threadIdx.x) >> 6;
  if (wid >= Nn) return;
  int lane = threadIdx.x & 63;
  int s = off[wid], t = off[wid+1];
  float acc = 0.f, cs = 0.f;
  for (int i = s; i < t; ++i){
    int e = csr[i];
    float mv = mask[e];
    acc += ea[(size_t)e*D_ + lane]*mv; cs += mv;
  }
  out[(size_t)wid*D_ + lane] = acc / (cs + 1.f);
}

// edge GEMM: ea_out[e] = relu(W @ [ea|nrep[row]|nrep[col]] + b)
__global__ __launch_bounds__(256) void k_gemm(
    const float* __restrict__ nrep, const float* __restrict__ ea_in,
    const int* __restrict__ rel, const float* __restrict__ emb,
    float* __restrict__ ea_out,
    const int* __restrict__ eidx,
    const short* __restrict__ Wp, const float* __restrict__ bias,
    int E, int first)
{
  __shared__ __align__(16) short in_tile[EB*KPAD];
  int tid = threadIdx.x;
  int e0 = blockIdx.x*EB;

  // zero pad region k=208..223 (16 bf16 per edge = 8 dwords; 32 edges * 8 = 256 dwords)
  {
    int e = tid >> 3, w = tid & 7;
    *reinterpret_cast<unsigned int*>(&in_tile[e*KPAD + 208 + w*2]) = 0u;
  }
  // vectorized staging: 52 float4 per edge
  for (int q = tid; q < EB*52; q += 256){
    int e = q / 52;
    int s = q - e*52;
    int ge = e0 + e;
    f32x4 v = {0.f,0.f,0.f,0.f};
    int k0;
    if (s < 16){
      k0 = s*4;
      if (ge < E){
        v = first ? *reinterpret_cast<const f32x4*>(&emb[rel[ge]*D_ + s*4])
                  : *reinterpret_cast<const f32x4*>(&ea_in[(size_t)ge*D_ + s*4]);
      }
    } else if (s < 34){
      int u = s - 16;
      k0 = 64 + u*4;
      if (ge < E) v = *reinterpret_cast<const f32x4*>(&nrep[(size_t)eidx[ge]*NR_STRIDE + u*4]);
    } else {
      int u = s - 34;
      k0 = 136 + u*4;
      if (ge < E) v = *reinterpret_cast<const f32x4*>(&nrep[(size_t)eidx[E+ge]*NR_STRIDE + u*4]);
    }
    u32x2 pk;
    pk.x = (unsigned int)f2bf(v.x) | ((unsigned int)f2bf(v.y) << 16);
    pk.y = (unsigned int)f2bf(v.z) | ((unsigned int)f2bf(v.w) << 16);
    *reinterpret_cast<u32x2*>(&in_tile[e*KPAD + k0]) = pk;
  }
  __syncthreads();

  int lane = tid & 63, wv = tid >> 6;
  int r = lane & 15, kg = lane >> 4;
  f32x4 acc0 = {0.f,0.f,0.f,0.f}, acc1 = {0.f,0.f,0.f,0.f};
  const short8* wp = reinterpret_cast<const short8*>(Wp) + (size_t)(wv*7)*64 + lane;
  #pragma unroll
  for (int kc = 0; kc < 7; ++kc){
    short8 bw = wp[(size_t)kc*64];
    short8 a0 = *reinterpret_cast<const short8*>(&in_tile[r*KPAD + kc*32 + kg*8]);
    short8 a1 = *reinterpret_cast<const short8*>(&in_tile[(16+r)*KPAD + kc*32 + kg*8]);
    acc0 = __builtin_amdgcn_mfma_f32_16x16x32_bf16(a0, bw, acc0, 0, 0, 0);
    acc1 = __builtin_amdgcn_mfma_f32_16x16x32_bf16(a1, bw, acc1, 0, 0, 0);
  }

  // epilogue: LDS bounce for coalesced float4 stores
  __syncthreads();
  float* otile = reinterpret_cast<float*>(in_tile);
  int c = wv*16 + r;
  float bc = bias[c];
  #pragma unroll
  for (int j = 0; j < 4; ++j){
    int er = kg*4 + j;               // C/D: row=(lane>>4)*4+j, col=lane&15
    float v0 = acc0[j] + bc; v0 = v0 > 0.f ? v0 : 0.f;
    float v1 = acc1[j] + bc; v1 = v1 > 0.f ? v1 : 0.f;
    otile[er*OPAD + c] = v0;
    otile[(16+er)*OPAD + c] = v1;
  }
  __syncthreads();
  #pragma unroll
  for (int h = 0; h < 2; ++h){
    int q = tid + h*256;
    int erow = q >> 4, c4 = (q & 15) << 2;
    int ge = e0 + erow;
    if (ge < E){
      f32x4 v = *reinterpret_cast<const f32x4*>(&otile[erow*OPAD + c4]);
      *reinterpret_cast<f32x4*>(&ea_out[(size_t)ge*D_ + c4]) = v;
    }
  }
}

// graph_emb: [segment_max over graph | nrep[head] | nrep[tail]]
__global__ void k_pool(const float* __restrict__ nrep_out, const int* __restrict__ head,
                       const int* __restrict__ counts, float* __restrict__ gout, int B){
  __shared__ float s[4][64];
  int g = blockIdx.x;
  int lane = threadIdx.x & 63, sub = threadIdx.x >> 6;
  int h = head[g]; int n = counts[g];
  float m = -3.402823466e38f;
  for (int i = sub; i < n; i += 4)
    m = fmaxf(m, nrep_out[(size_t)(h+i)*D_ + lane]);
  s[sub][lane] = m;
  __syncthreads();
  if (sub == 0){
    m = fmaxf(fmaxf(s[0][lane], s[1][lane]), fmaxf(s[2][lane], s[3][lane]));
    gout[(size_t)g*192 + lane]       = m;
    gout[(size_t)g*192 + 64  + lane] = nrep_out[(size_t)h*D_ + lane];
    gout[(size_t)g*192 + 128 + lane] = nrep_out[(size_t)(h+1)*D_ + lane];
  }
}

extern "C" void kernel_launch(void* const* d_in, const int* in_sizes, int n_in,
                              void* d_out, int out_size, void* d_ws, size_t ws_size,
                              hipStream_t stream)
{
  const float* x    = (const float*)d_in[0];
  const int*   eidx = (const int*)d_in[1];
  const int*   erel = (const int*)d_in[2];
  const int*   batch= (const int*)d_in[3];
  const float* mask = (const float*)d_in[4];
  const float* emb  = (const float*)d_in[5];
  const float* W0   = (const float*)d_in[6];
  const float* b0   = (const float*)d_in[7];
  const float* W1   = (const float*)d_in[8];
  const float* b1   = (const float*)d_in[9];
  const float* W2   = (const float*)d_in[10];
  const float* b2   = (const float*)d_in[11];

  int N = in_sizes[0] / NODE_DIM_;
  int E = in_sizes[2];
  int B = (int)(((long long)out_size - (long long)N*D_ - (long long)E*D_) / 192);

  float* out_ge   = (float*)d_out;                 // B*192
  float* out_nrep = out_ge + (size_t)B*192;        // N*64
  float* out_ea   = out_nrep + (size_t)N*D_;       // E*64

  char* w = (char*)d_ws;
  auto alloc = [&](size_t bytes)->char*{ char* p = w; w += (bytes + 255) & ~(size_t)255; return p; };
  float* nrep   = (float*)alloc((size_t)N*NR_STRIDE*4);
  int*   cnt_i  = (int*)  alloc((size_t)N*4);
  int*   off    = (int*)  alloc((size_t)(N+1)*4);
  int*   fpos   = (int*)  alloc((size_t)N*4);
  int*   csr    = (int*)  alloc((size_t)E*4);
  int*   counts = (int*)  alloc((size_t)B*4);
  int*   head   = (int*)  alloc((size_t)B*4);
  short* Wp     = (short*)alloc((size_t)3*WP_PER_LAYER*2);

  hipMemsetAsync(nrep,   0, (size_t)N*NR_STRIDE*4, stream);
  hipMemsetAsync(cnt_i,  0, (size_t)N*4, stream);
  hipMemsetAsync(fpos,   0, (size_t)N*4, stream);
  hipMemsetAsync(counts, 0, (size_t)B*4, stream);

  const int* ecol = eidx + E;

  k_count_batch<<<(N+255)/256, 256, 0, stream>>>(batch, counts, N);
  k_scan_heads <<<1, 1024, 0, stream>>>(counts, head, B);
  k_x0         <<<(B*2*NODE_DIM_+255)/256, 256, 0, stream>>>(head, x, nrep, B);
  k_cnt_int    <<<(E+255)/256, 256, 0, stream>>>(ecol, cnt_i, E);
  k_scan_off   <<<1, 1024, 0, stream>>>(cnt_i, off, N);
  k_fill       <<<(E+255)/256, 256, 0, stream>>>(ecol, off, fpos, csr, E);
  k_pack_w     <<<(3*WP_PER_LAYER+255)/256, 256, 0, stream>>>(W0, W1, W2, Wp);

  const float* bs[3] = {b0, b1, b2};
  int nblk_g = (E + EB - 1) / EB;
  int nblk_a = (N + 3) / 4;
  for (int l = 0; l < 3; ++l){
    k_agg<<<nblk_a, 256, 0, stream>>>(out_ea, erel, emb, csr, off, mask, nrep, N, (l==0)?1:0);
    k_gemm<<<nblk_g, 256, 0, stream>>>(nrep, out_ea, erel, emb, out_ea, eidx,
                                       Wp + (size_t)l*WP_PER_LAYER, bs[l], E, (l==0)?1:0);
  }
  k_agg_final<<<nblk_a, 256, 0, stream>>>(out_ea, csr, off, mask, out_nrep, N);
  k_pool<<<B, 256, 0, stream>>>(out_nrep, head, counts, out_ge, B);
}

// Round 4
// 936.938 us; speedup vs baseline: 1.8214x; 1.4559x over previous
//
#include <hip/hip_runtime.h>
#include <stdint.h>

typedef __attribute__((ext_vector_type(8))) short short8;
typedef __attribute__((ext_vector_type(4))) float f32x4;
typedef __attribute__((ext_vector_type(2))) float f32x2;
typedef __attribute__((ext_vector_type(2))) unsigned int u32x2;

#define D_ 64
#define NODE_DIM_ 6
#define INF_ 204          // IN_FEAT = 3*64 + 2*6
#define NF_STRIDE 72      // node feature row stride f32 (70 used + 2 pad)
#define EB 64             // edges per GEMM block
#define WEA_PER_LAYER 4096    // 4nt*2kc*64lane*8
#define WN_PER_LAYER 12288    // 8nt*3kc*64lane*8

__device__ __forceinline__ unsigned short f2bf(float f){
  uint32_t u = __float_as_uint(f);
  u += 0x7fffu + ((u >> 16) & 1u);   // RNE (finite values only)
  return (unsigned short)(u >> 16);
}

__global__ void k_count_batch(const int* __restrict__ batch, int* __restrict__ counts, int n){
  int i = blockIdx.x*256 + threadIdx.x;
  if (i < n) atomicAdd(&counts[batch[i]], 1);
}

__global__ void k_scan_heads(const int* __restrict__ counts, int* __restrict__ head, int B){
  __shared__ int s[1024];
  int t = threadIdx.x;
  int v = (t < B) ? counts[t] : 0;
  s[t] = v;
  __syncthreads();
  for (int off = 1; off < 1024; off <<= 1){
    int u = (t >= off) ? s[t-off] : 0;
    __syncthreads();
    s[t] += u;
    __syncthreads();
  }
  if (t < B) head[t] = s[t] - v;
}

// ---- CSR build (by col) ----
__global__ void k_cnt_int(const int* __restrict__ col, int* __restrict__ cnt, int E){
  int e = blockIdx.x*256 + threadIdx.x;
  if (e < E) atomicAdd(&cnt[col[e]], 1);
}

__global__ void k_scan_off(const int* __restrict__ cnt, int* __restrict__ off, int Nn){
  __shared__ int s[1024];
  int t = threadIdx.x;
  const int CH = (Nn + 1024) / 1024;
  int base = t*CH;
  int sum = 0;
  for (int i = 0; i < CH; ++i){ int idx = base+i; if (idx < Nn) sum += cnt[idx]; }
  s[t] = sum;
  __syncthreads();
  for (int o = 1; o < 1024; o <<= 1){
    int u = (t >= o) ? s[t-o] : 0;
    __syncthreads();
    s[t] += u;
    __syncthreads();
  }
  int run = (t == 0) ? 0 : s[t-1];
  for (int i = 0; i < CH; ++i){
    int idx = base+i;
    if (idx <= Nn){ off[idx] = run; if (idx < Nn) run += cnt[idx]; }
  }
}

__global__ void k_fill(const int* __restrict__ col, const int* __restrict__ off,
                       int* __restrict__ fpos, int* __restrict__ csr, int E){
  int e = blockIdx.x*256 + threadIdx.x;
  if (e >= E) return;
  int c = col[e];
  int p = atomicAdd(&fpos[c], 1);
  csr[off[c] + p] = e;
}

// permute rel/mask into CSR order (sequential reads in agg)
__global__ void k_perm(const int* __restrict__ csr, const int* __restrict__ rel,
                       const float* __restrict__ mask, int* __restrict__ relp,
                       float* __restrict__ maskp, int E){
  int i = blockIdx.x*256 + threadIdx.x;
  if (i >= E) return;
  int e = csr[i];
  relp[i] = rel[e];
  maskp[i] = mask[e];
}

// x0 (head/tail rows of x) -> nf cols 64..69
__global__ void k_x0(const int* __restrict__ head, const float* __restrict__ x,
                     float* __restrict__ nf, int B){
  int idx = blockIdx.x*256 + threadIdx.x;
  if (idx >= B*2*NODE_DIM_) return;
  int g = idx / (2*NODE_DIM_);
  int j = idx % (2*NODE_DIM_);
  int node = head[g] + j / NODE_DIM_;
  int c = j % NODE_DIM_;
  nf[(size_t)node*NF_STRIDE + D_ + c] = x[node*NODE_DIM_ + c];
}

// pack W_ea (c, 140+k) and W_node (Yrow: c,k | Ycol: c-64, 70+k) into MFMA B-frag order
__global__ void k_pack_w(const float* __restrict__ W0, const float* __restrict__ W1,
                         const float* __restrict__ W2,
                         unsigned short* __restrict__ Wea, unsigned short* __restrict__ Wn){
  int idx = blockIdx.x*256 + threadIdx.x;
  if (idx < 3*WEA_PER_LAYER){
    int l = idx / WEA_PER_LAYER;
    int rem = idx % WEA_PER_LAYER;
    const float* W = (l==0) ? W0 : ((l==1) ? W1 : W2);
    int i = rem & 7, s = rem >> 3;
    int lane = s & 63, t = s >> 6;          // t = nt*2 + kc
    int kc = t & 1, nt = t >> 1;
    int n = lane & 15, kg = lane >> 4;
    int k = kc*32 + kg*8 + i;               // 0..63
    int c = nt*16 + n;                      // 0..63
    Wea[idx] = f2bf(W[c*INF_ + 140 + k]);
    return;
  }
  int idx2 = idx - 3*WEA_PER_LAYER;
  if (idx2 >= 3*WN_PER_LAYER) return;
  int l = idx2 / WN_PER_LAYER;
  int rem = idx2 % WN_PER_LAYER;
  const float* W = (l==0) ? W0 : ((l==1) ? W1 : W2);
  int i = rem & 7, s = rem >> 3;
  int lane = s & 63, t = s >> 6;            // t = nt*3 + kc
  int kc = t % 3, nt = t / 3;               // nt 0..7
  int n = lane & 15, kg = lane >> 4;
  int k = kc*32 + kg*8 + i;                 // 0..95
  int c = nt*16 + n;                        // 0..127
  float v = 0.f;
  if (k < 70) v = (nt < 4) ? W[c*INF_ + k] : W[(c-64)*INF_ + 70 + k];
  Wn[idx2] = f2bf(v);
}

__global__ void k_pack_emb(const float* __restrict__ emb, unsigned short* __restrict__ emb_bf, int n){
  int i = blockIdx.x*256 + threadIdx.x;
  if (i < n) emb_bf[i] = f2bf(emb[i]);
}

// ---- aggregation (gather via CSR), 2 edges per iter (half-wave each) ----
__global__ __launch_bounds__(256) void k_agg0(
    const float* __restrict__ emb, const int* __restrict__ relp,
    const int* __restrict__ off, const float* __restrict__ maskp,
    float* __restrict__ nf, int Nn)
{
  int wid = (blockIdx.x*256 + threadIdx.x) >> 6;
  if (wid >= Nn) return;
  int lane = threadIdx.x & 63;
  int half = lane >> 5, c2 = lane & 31;
  int s = off[wid], t = off[wid+1];
  float ax = 0.f, ay = 0.f, cs = 0.f;
  for (int i = s; i < t; i += 2){
    int ii = i + half;
    if (ii < t){
      float mv = maskp[ii];
      f32x2 v = *reinterpret_cast<const f32x2*>(&emb[relp[ii]*D_ + c2*2]);
      ax += v.x*mv; ay += v.y*mv; cs += mv;
    }
  }
  ax += __shfl_xor(ax, 32); ay += __shfl_xor(ay, 32); cs += __shfl_xor(cs, 32);
  if (lane < 32){
    float inv = 1.f/(cs + 1.f);
    f32x2 w = {ax*inv, ay*inv};
    *reinterpret_cast<f32x2*>(&nf[(size_t)wid*NF_STRIDE + c2*2]) = w;
  }
}

__global__ __launch_bounds__(256) void k_agg_bf(
    const unsigned short* __restrict__ ea, const int* __restrict__ csr,
    const int* __restrict__ off, const float* __restrict__ maskp,
    float* __restrict__ nf, int Nn)
{
  int wid = (blockIdx.x*256 + threadIdx.x) >> 6;
  if (wid >= Nn) return;
  int lane = threadIdx.x & 63;
  int half = lane >> 5, c2 = lane & 31;
  int s = off[wid], t = off[wid+1];
  float ax = 0.f, ay = 0.f, cs = 0.f;
  for (int i = s; i < t; i += 2){
    int ii = i + half;
    int e = 0; float mv = 0.f;
    if (ii < t){ e = csr[ii]; mv = maskp[ii]; }
    uint32_t u = *reinterpret_cast<const uint32_t*>(&ea[(size_t)e*D_ + c2*2]);
    ax += __uint_as_float(u << 16) * mv;
    ay += __uint_as_float(u & 0xffff0000u) * mv;
    cs += mv;
  }
  ax += __shfl_xor(ax, 32); ay += __shfl_xor(ay, 32); cs += __shfl_xor(cs, 32);
  if (lane < 32){
    float inv = 1.f/(cs + 1.f);
    f32x2 w = {ax*inv, ay*inv};
    *reinterpret_cast<f32x2*>(&nf[(size_t)wid*NF_STRIDE + c2*2]) = w;
  }
}

__global__ __launch_bounds__(256) void k_agg_final(
    const float* __restrict__ ea32, const int* __restrict__ csr,
    const int* __restrict__ off, const float* __restrict__ maskp,
    float* __restrict__ out, int Nn)
{
  int wid = (blockIdx.x*256 + threadIdx.x) >> 6;
  if (wid >= Nn) return;
  int lane = threadIdx.x & 63;
  int half = lane >> 5, c2 = lane & 31;
  int s = off[wid], t = off[wid+1];
  float ax = 0.f, ay = 0.f, cs = 0.f;
  for (int i = s; i < t; i += 2){
    int ii = i + half;
    if (ii < t){
      float mv = maskp[ii];
      f32x2 v = *reinterpret_cast<const f32x2*>(&ea32[(size_t)csr[ii]*D_ + c2*2]);
      ax += v.x*mv; ay += v.y*mv; cs += mv;
    }
  }
  ax += __shfl_xor(ax, 32); ay += __shfl_xor(ay, 32); cs += __shfl_xor(cs, 32);
  if (lane < 32){
    float inv = 1.f/(cs + 1.f);
    f32x2 w = {ax*inv, ay*inv};
    *reinterpret_cast<f32x2*>(&out[(size_t)wid*D_ + c2*2]) = w;
  }
}

// ---- per-node Y GEMM: Ybuf[n][0:64]=W_row@nf+b, [64:128]=W_col@nf ----
__global__ __launch_bounds__(256) void k_ynode(
    const float* __restrict__ nf, const unsigned short* __restrict__ Wn,
    const float* __restrict__ bias, float* __restrict__ Ybuf, int Nn)
{
  __shared__ __align__(16) short tile[32*104];
  int tid = threadIdx.x;
  int n0 = blockIdx.x*32;
  if (tid < 128){
    int e = tid >> 2, w = tid & 3;
    *reinterpret_cast<short8*>(&tile[e*104 + 72 + w*8]) = short8{0,0,0,0,0,0,0,0};
  }
  const f32x4* nf4 = reinterpret_cast<const f32x4*>(nf);
  for (int s = tid; s < 32*18; s += 256){
    int e = s/18, q = s - e*18;
    f32x4 v = {0.f,0.f,0.f,0.f};
    if (n0 + e < Nn) v = nf4[(size_t)(n0+e)*18 + q];
    u32x2 pk;
    pk.x = (unsigned)f2bf(v.x) | ((unsigned)f2bf(v.y) << 16);
    pk.y = (unsigned)f2bf(v.z) | ((unsigned)f2bf(v.w) << 16);
    *reinterpret_cast<u32x2*>(&tile[e*104 + q*4]) = pk;
  }
  __syncthreads();
  int lane = tid & 63, wv = tid >> 6;
  int r16 = lane & 15, kg = lane >> 4;
  const short8* W8 = reinterpret_cast<const short8*>(Wn);
  f32x4 acc[2][2] = {};
  #pragma unroll
  for (int kc = 0; kc < 3; ++kc){
    short8 a0 = *reinterpret_cast<const short8*>(&tile[r16*104 + kc*32 + kg*8]);
    short8 a1 = *reinterpret_cast<const short8*>(&tile[(16+r16)*104 + kc*32 + kg*8]);
    #pragma unroll
    for (int t = 0; t < 2; ++t){
      int nt = wv*2 + t;
      short8 wf = W8[(nt*3 + kc)*64 + lane];
      acc[0][t] = __builtin_amdgcn_mfma_f32_16x16x32_bf16(a0, wf, acc[0][t], 0,0,0);
      acc[1][t] = __builtin_amdgcn_mfma_f32_16x16x32_bf16(a1, wf, acc[1][t], 0,0,0);
    }
  }
  #pragma unroll
  for (int t = 0; t < 2; ++t){
    int nt = wv*2 + t;
    int c = nt*16 + r16;
    float b = (nt < 4) ? bias[c] : 0.f;
    #pragma unroll
    for (int m = 0; m < 2; ++m)
      #pragma unroll
      for (int j = 0; j < 4; ++j){
        int node = n0 + m*16 + kg*4 + j;
        if (node < Nn) Ybuf[(size_t)node*128 + c] = acc[m][t][j] + b;
      }
  }
}

// ---- edge GEMM: ea' = relu(W_ea@ea + Yrow[row] + Ycol[col]) ----
template<int FIRST, int FOUT>
__global__ __launch_bounds__(256) void k_gemm(
    const unsigned short* __restrict__ ea_bf, const unsigned short* __restrict__ emb_bf,
    const float* __restrict__ Ybuf,
    unsigned short* __restrict__ ea_out_bf, float* __restrict__ ea_out_f32,
    const int* __restrict__ eidx, const int* __restrict__ erel,
    const unsigned short* __restrict__ Wea, int E)
{
  __shared__ __align__(16) float stile[EB*68];
  __shared__ int s_row[EB], s_col[EB], s_rel[EB];
  int tid = threadIdx.x;
  int e0 = blockIdx.x*EB;
  if (tid < EB){
    int ge = e0 + tid;
    bool ok = ge < E;
    s_row[tid] = ok ? eidx[ge] : 0;
    s_col[tid] = ok ? eidx[E + ge] : 0;
    s_rel[tid] = (FIRST && ok) ? erel[ge] : 0;
  }
  __syncthreads();
  const f32x4* Yb4 = reinterpret_cast<const f32x4*>(Ybuf);
  f32x4* st4 = reinterpret_cast<f32x4*>(stile);
  #pragma unroll
  for (int h = 0; h < 4; ++h){
    int s = tid + h*256;
    int e = s >> 4, q = s & 15;
    f32x4 a = Yb4[(size_t)s_row[e]*32 + q];
    f32x4 b = Yb4[(size_t)s_col[e]*32 + 16 + q];
    st4[e*17 + q] = a + b;
  }
  int lane = tid & 63, wv = tid >> 6;
  int r16 = lane & 15, kg = lane >> 4;
  const short8* W8 = reinterpret_cast<const short8*>(Wea);
  short8 wf[4][2];
  #pragma unroll
  for (int nt = 0; nt < 4; ++nt)
    #pragma unroll
    for (int kc = 0; kc < 2; ++kc)
      wf[nt][kc] = W8[(nt*2 + kc)*64 + lane];
  f32x4 acc[4] = {};
  #pragma unroll
  for (int kc = 0; kc < 2; ++kc){
    short8 a;
    if (FIRST){
      a = *reinterpret_cast<const short8*>(&emb_bf[(size_t)s_rel[wv*16 + r16]*D_ + kc*32 + kg*8]);
    } else {
      int eA = e0 + wv*16 + r16; if (eA >= E) eA = E-1;
      a = *reinterpret_cast<const short8*>(&ea_bf[(size_t)eA*D_ + kc*32 + kg*8]);
    }
    #pragma unroll
    for (int nt = 0; nt < 4; ++nt)
      acc[nt] = __builtin_amdgcn_mfma_f32_16x16x32_bf16(a, wf[nt][kc], acc[nt], 0,0,0);
  }
  __syncthreads();   // <-- FIX: stile staging (writes by all waves) must complete before epilogue reads
  float v[4][4];
  #pragma unroll
  for (int nt = 0; nt < 4; ++nt)
    #pragma unroll
    for (int j = 0; j < 4; ++j){
      int et = wv*16 + kg*4 + j;           // C/D: row=(lane>>4)*4+j, col=lane&15
      float x = acc[nt][j] + stile[et*68 + nt*16 + r16];
      v[nt][j] = x > 0.f ? x : 0.f;
    }
  __syncthreads();
  if (FOUT == 0){
    unsigned short* ob = reinterpret_cast<unsigned short*>(stile);  // [64][72]
    #pragma unroll
    for (int nt = 0; nt < 4; ++nt)
      #pragma unroll
      for (int j = 0; j < 4; ++j)
        ob[(wv*16 + kg*4 + j)*72 + nt*16 + r16] = f2bf(v[nt][j]);
    __syncthreads();
    #pragma unroll
    for (int h = 0; h < 2; ++h){
      int s = tid + h*256;
      int e = s >> 3, w = s & 7;
      int ge = e0 + e;
      if (ge < E)
        *reinterpret_cast<short8*>(&ea_out_bf[(size_t)ge*D_ + w*8]) =
          *reinterpret_cast<const short8*>(&ob[e*72 + w*8]);
    }
  } else {
    #pragma unroll
    for (int nt = 0; nt < 4; ++nt)
      #pragma unroll
      for (int j = 0; j < 4; ++j)
        stile[(wv*16 + kg*4 + j)*68 + nt*16 + r16] = v[nt][j];
    __syncthreads();
    f32x4* out4 = reinterpret_cast<f32x4*>(ea_out_f32);
    #pragma unroll
    for (int h = 0; h < 4; ++h){
      int s = tid + h*256;
      int e = s >> 4, q = s & 15;
      int ge = e0 + e;
      if (ge < E) out4[(size_t)ge*16 + q] = st4[e*17 + q];
    }
  }
}

__global__ void k_pool(const float* __restrict__ nrep_out, const int* __restrict__ head,
                       const int* __restrict__ counts, float* __restrict__ gout, int B){
  __shared__ float s[4][64];
  int g = blockIdx.x;
  int lane = threadIdx.x & 63, sub = threadIdx.x >> 6;
  int h = head[g]; int n = counts[g];
  float m = -3.402823466e38f;
  for (int i = sub; i < n; i += 4)
    m = fmaxf(m, nrep_out[(size_t)(h+i)*D_ + lane]);
  s[sub][lane] = m;
  __syncthreads();
  if (sub == 0){
    m = fmaxf(fmaxf(s[0][lane], s[1][lane]), fmaxf(s[2][lane], s[3][lane]));
    gout[(size_t)g*192 + lane]       = m;
    gout[(size_t)g*192 + 64  + lane] = nrep_out[(size_t)h*D_ + lane];
    gout[(size_t)g*192 + 128 + lane] = nrep_out[(size_t)(h+1)*D_ + lane];
  }
}

extern "C" void kernel_launch(void* const* d_in, const int* in_sizes, int n_in,
                              void* d_out, int out_size, void* d_ws, size_t ws_size,
                              hipStream_t stream)
{
  const float* x    = (const float*)d_in[0];
  const int*   eidx = (const int*)d_in[1];
  const int*   erel = (const int*)d_in[2];
  const int*   batch= (const int*)d_in[3];
  const float* mask = (const float*)d_in[4];
  const float* emb  = (const float*)d_in[5];
  const float* W0   = (const float*)d_in[6];
  const float* b0   = (const float*)d_in[7];
  const float* W1   = (const float*)d_in[8];
  const float* b1   = (const float*)d_in[9];
  const float* W2   = (const float*)d_in[10];
  const float* b2   = (const float*)d_in[11];

  int N = in_sizes[0] / NODE_DIM_;
  int E = in_sizes[2];
  int B = (int)(((long long)out_size - (long long)N*D_ - (long long)E*D_) / 192);

  float* out_ge   = (float*)d_out;                 // B*192
  float* out_nrep = out_ge + (size_t)B*192;        // N*64
  float* out_ea   = out_nrep + (size_t)N*D_;       // E*64  (f32 final)

  char* w = (char*)d_ws;
  auto alloc = [&](size_t bytes)->char*{ char* p = w; w += (bytes + 255) & ~(size_t)255; return p; };
  unsigned short* ea_bf = (unsigned short*)alloc((size_t)E*D_*2);   // 102.4 MB
  float* nf     = (float*)alloc((size_t)N*NF_STRIDE*4);             // 14.4 MB
  float* Ybuf   = (float*)alloc((size_t)N*128*4);                   // 25.6 MB
  int*   cnt_i  = (int*)  alloc((size_t)N*4);
  int*   off    = (int*)  alloc((size_t)(N+1)*4);
  int*   fpos   = (int*)  alloc((size_t)N*4);
  int*   csr    = (int*)  alloc((size_t)E*4);
  int*   relp   = (int*)  alloc((size_t)E*4);
  float* maskp  = (float*)alloc((size_t)E*4);
  int*   counts = (int*)  alloc((size_t)B*4);
  int*   head   = (int*)  alloc((size_t)B*4);
  unsigned short* Wea = (unsigned short*)alloc((size_t)3*WEA_PER_LAYER*2);
  unsigned short* Wn  = (unsigned short*)alloc((size_t)3*WN_PER_LAYER*2);
  unsigned short* emb_bf = (unsigned short*)alloc((size_t)200*D_*2 + 256);

  hipMemsetAsync(nf,     0, (size_t)N*NF_STRIDE*4, stream);
  hipMemsetAsync(cnt_i,  0, (size_t)N*4, stream);
  hipMemsetAsync(fpos,   0, (size_t)N*4, stream);
  hipMemsetAsync(counts, 0, (size_t)B*4, stream);

  const int* ecol = eidx + E;

  k_count_batch<<<(N+255)/256, 256, 0, stream>>>(batch, counts, N);
  k_scan_heads <<<1, 1024, 0, stream>>>(counts, head, B);
  k_x0         <<<(B*2*NODE_DIM_+255)/256, 256, 0, stream>>>(head, x, nf, B);
  k_cnt_int    <<<(E+255)/256, 256, 0, stream>>>(ecol, cnt_i, E);
  k_scan_off   <<<1, 1024, 0, stream>>>(cnt_i, off, N);
  k_fill       <<<(E+255)/256, 256, 0, stream>>>(ecol, off, fpos, csr, E);
  k_perm       <<<(E+255)/256, 256, 0, stream>>>(csr, erel, mask, relp, maskp, E);
  k_pack_w     <<<(3*(WEA_PER_LAYER+WN_PER_LAYER)+255)/256, 256, 0, stream>>>(W0, W1, W2, Wea, Wn);
  k_pack_emb   <<<(200*D_+255)/256, 256, 0, stream>>>(emb, emb_bf, 200*D_);

  int nblk_g = (E + EB - 1) / EB;
  int nblk_a = (N + 3) / 4;
  int nblk_y = (N + 31) / 32;

  // layer 0
  k_agg0 <<<nblk_a, 256, 0, stream>>>(emb, relp, off, maskp, nf, N);
  k_ynode<<<nblk_y, 256, 0, stream>>>(nf, Wn, b0, Ybuf, N);
  k_gemm<1,0><<<nblk_g, 256, 0, stream>>>(ea_bf, emb_bf, Ybuf, ea_bf, out_ea, eidx, erel, Wea, E);
  // layer 1
  k_agg_bf<<<nblk_a, 256, 0, stream>>>(ea_bf, csr, off, maskp, nf, N);
  k_ynode<<<nblk_y, 256, 0, stream>>>(nf, Wn + WN_PER_LAYER, b1, Ybuf, N);
  k_gemm<0,0><<<nblk_g, 256, 0, stream>>>(ea_bf, emb_bf, Ybuf, ea_bf, out_ea, eidx, erel, Wea + WEA_PER_LAYER, E);
  // layer 2 (f32 output to d_out)
  k_agg_bf<<<nblk_a, 256, 0, stream>>>(ea_bf, csr, off, maskp, nf, N);
  k_ynode<<<nblk_y, 256, 0, stream>>>(nf, Wn + 2*WN_PER_LAYER, b2, Ybuf, N);
  k_gemm<0,1><<<nblk_g, 256, 0, stream>>>(ea_bf, emb_bf, Ybuf, ea_bf, out_ea, eidx, erel, Wea + 2*WEA_PER_LAYER, E);

  k_agg_final<<<nblk_a, 256, 0, stream>>>(out_ea, csr, off, maskp, out_nrep, N);
  k_pool<<<B, 256, 0, stream>>>(out_nrep, head, counts, out_ge, B);
}

// Round 5
// 827.776 us; speedup vs baseline: 2.0616x; 1.1319x over previous
//
#include <hip/hip_runtime.h>
#include <stdint.h>

typedef __attribute__((ext_vector_type(8))) short short8;
typedef __attribute__((ext_vector_type(4))) float f32x4;
typedef __attribute__((ext_vector_type(2))) float f32x2;
typedef __attribute__((ext_vector_type(2))) unsigned int u32x2;

#define D_ 64
#define NODE_DIM_ 6
#define INF_ 204          // IN_FEAT = 3*64 + 2*6
#define NF_STRIDE 72      // node feature row stride f32 (70 used + 2 pad)
#define EB 64             // edges per GEMM block
#define WEA_PER_LAYER 4096    // 4nt*2kc*64lane*8
#define WN_PER_LAYER 12288    // 8nt*3kc*64lane*8

__device__ __forceinline__ unsigned int f2bf(float f){
  uint32_t u = __float_as_uint(f);
  u += 0x7fffu + ((u >> 16) & 1u);   // RNE (finite values only)
  return u >> 16;
}

__global__ void k_count_batch(const int* __restrict__ batch, int* __restrict__ counts, int n){
  int i = blockIdx.x*256 + threadIdx.x;
  if (i < n) atomicAdd(&counts[batch[i]], 1);
}

__global__ void k_scan_heads(const int* __restrict__ counts, int* __restrict__ head, int B){
  __shared__ int s[1024];
  int t = threadIdx.x;
  int v = (t < B) ? counts[t] : 0;
  s[t] = v;
  __syncthreads();
  for (int off = 1; off < 1024; off <<= 1){
    int u = (t >= off) ? s[t-off] : 0;
    __syncthreads();
    s[t] += u;
    __syncthreads();
  }
  if (t < B) head[t] = s[t] - v;
}

// ---- CSR build (by col) ----
__global__ void k_cnt_int(const int* __restrict__ col, int* __restrict__ cnt, int E){
  int e = blockIdx.x*256 + threadIdx.x;
  if (e < E) atomicAdd(&cnt[col[e]], 1);
}

__global__ void k_scan_off(const int* __restrict__ cnt, int* __restrict__ off, int Nn){
  __shared__ int s[1024];
  int t = threadIdx.x;
  const int CH = (Nn + 1024) / 1024;
  int base = t*CH;
  int sum = 0;
  for (int i = 0; i < CH; ++i){ int idx = base+i; if (idx < Nn) sum += cnt[idx]; }
  s[t] = sum;
  __syncthreads();
  for (int o = 1; o < 1024; o <<= 1){
    int u = (t >= o) ? s[t-o] : 0;
    __syncthreads();
    s[t] += u;
    __syncthreads();
  }
  int run = (t == 0) ? 0 : s[t-1];
  for (int i = 0; i < CH; ++i){
    int idx = base+i;
    if (idx <= Nn){ off[idx] = run; if (idx < Nn) run += cnt[idx]; }
  }
}

// scatter edge data into CSR order (one pass; replaces fill+perm)
__global__ void k_fill(const int* __restrict__ row, const int* __restrict__ col,
                       const int* __restrict__ rel, const float* __restrict__ mask,
                       const int* __restrict__ off, int* __restrict__ fpos,
                       int* __restrict__ csr, int* __restrict__ rowp, int* __restrict__ colp,
                       int* __restrict__ relp, float* __restrict__ maskp, int E){
  int e = blockIdx.x*256 + threadIdx.x;
  if (e >= E) return;
  int c = col[e];
  int p = atomicAdd(&fpos[c], 1);
  int pos = off[c] + p;
  csr[pos]  = e;
  rowp[pos] = row[e];
  colp[pos] = c;
  relp[pos] = rel[e];
  maskp[pos]= mask[e];
}

// x0 (head/tail rows of x) -> nf cols 64..69
__global__ void k_x0(const int* __restrict__ head, const float* __restrict__ x,
                     float* __restrict__ nf, int B){
  int idx = blockIdx.x*256 + threadIdx.x;
  if (idx >= B*2*NODE_DIM_) return;
  int g = idx / (2*NODE_DIM_);
  int j = idx % (2*NODE_DIM_);
  int node = head[g] + j / NODE_DIM_;
  int c = j % NODE_DIM_;
  nf[(size_t)node*NF_STRIDE + D_ + c] = x[node*NODE_DIM_ + c];
}

// pack W_ea (c, 140+k) and W_node (Yrow: c,k | Ycol: c-64, 70+k) into MFMA B-frag order
__global__ void k_pack_w(const float* __restrict__ W0, const float* __restrict__ W1,
                         const float* __restrict__ W2,
                         unsigned short* __restrict__ Wea, unsigned short* __restrict__ Wn){
  int idx = blockIdx.x*256 + threadIdx.x;
  if (idx < 3*WEA_PER_LAYER){
    int l = idx / WEA_PER_LAYER;
    int rem = idx % WEA_PER_LAYER;
    const float* W = (l==0) ? W0 : ((l==1) ? W1 : W2);
    int i = rem & 7, s = rem >> 3;
    int lane = s & 63, t = s >> 6;          // t = nt*2 + kc
    int kc = t & 1, nt = t >> 1;
    int n = lane & 15, kg = lane >> 4;
    int k = kc*32 + kg*8 + i;               // 0..63
    int c = nt*16 + n;                      // 0..63
    Wea[idx] = (unsigned short)f2bf(W[c*INF_ + 140 + k]);
    return;
  }
  int idx2 = idx - 3*WEA_PER_LAYER;
  if (idx2 >= 3*WN_PER_LAYER) return;
  int l = idx2 / WN_PER_LAYER;
  int rem = idx2 % WN_PER_LAYER;
  const float* W = (l==0) ? W0 : ((l==1) ? W1 : W2);
  int i = rem & 7, s = rem >> 3;
  int lane = s & 63, t = s >> 6;            // t = nt*3 + kc
  int kc = t % 3, nt = t / 3;               // nt 0..7
  int n = lane & 15, kg = lane >> 4;
  int k = kc*32 + kg*8 + i;                 // 0..95
  int c = nt*16 + n;                        // 0..127
  float v = 0.f;
  if (k < 70) v = (nt < 4) ? W[c*INF_ + k] : W[(c-64)*INF_ + 70 + k];
  Wn[idx2] = (unsigned short)f2bf(v);
}

__global__ void k_pack_emb(const float* __restrict__ emb, unsigned short* __restrict__ emb_bf, int n){
  int i = blockIdx.x*256 + threadIdx.x;
  if (i < n) emb_bf[i] = (unsigned short)f2bf(emb[i]);
}

// ---- sequential CSR aggregation: 4 edges/iter, 16 lanes/edge (u32x2 = 4 bf16 each) ----
__global__ __launch_bounds__(256) void k_agg_seq(
    const unsigned short* __restrict__ eap, const int* __restrict__ off,
    const float* __restrict__ maskp, float* __restrict__ outp,
    int ostride, int Nn)
{
  int wid = (blockIdx.x*256 + threadIdx.x) >> 6;
  if (wid >= Nn) return;
  int lane = threadIdx.x & 63;
  int sub = lane >> 4, q = lane & 15;
  int s = off[wid], t = off[wid+1];
  float a0=0.f,a1=0.f,a2=0.f,a3=0.f, cs=0.f;
  for (int i = s; i < t; i += 4){
    int ii = i + sub;
    float mv = (ii < t) ? maskp[ii] : 0.f;
    int ie = (ii < t) ? ii : s;
    u32x2 u = *reinterpret_cast<const u32x2*>(&eap[(size_t)ie*D_ + q*4]);
    a0 += __uint_as_float(u.x << 16) * mv;
    a1 += __uint_as_float(u.x & 0xffff0000u) * mv;
    a2 += __uint_as_float(u.y << 16) * mv;
    a3 += __uint_as_float(u.y & 0xffff0000u) * mv;
    cs += mv;
  }
  a0 += __shfl_xor(a0,16); a1 += __shfl_xor(a1,16); a2 += __shfl_xor(a2,16);
  a3 += __shfl_xor(a3,16); cs += __shfl_xor(cs,16);
  a0 += __shfl_xor(a0,32); a1 += __shfl_xor(a1,32); a2 += __shfl_xor(a2,32);
  a3 += __shfl_xor(a3,32); cs += __shfl_xor(cs,32);
  if (sub == 0){
    float inv = 1.f/(cs + 1.f);
    f32x4 w = {a0*inv, a1*inv, a2*inv, a3*inv};
    *reinterpret_cast<f32x4*>(&outp[(size_t)wid*ostride + q*4]) = w;
  }
}

// layer-0 aggregation: emb[relp[i]] gather (f32, table is L1/L2-resident)
__global__ __launch_bounds__(256) void k_agg0_seq(
    const float* __restrict__ emb, const int* __restrict__ relp,
    const int* __restrict__ off, const float* __restrict__ maskp,
    float* __restrict__ nf, int Nn)
{
  int wid = (blockIdx.x*256 + threadIdx.x) >> 6;
  if (wid >= Nn) return;
  int lane = threadIdx.x & 63;
  int sub = lane >> 4, q = lane & 15;
  int s = off[wid], t = off[wid+1];
  float a0=0.f,a1=0.f,a2=0.f,a3=0.f, cs=0.f;
  for (int i = s; i < t; i += 4){
    int ii = i + sub;
    float mv = (ii < t) ? maskp[ii] : 0.f;
    int r = (ii < t) ? relp[ii] : 0;
    f32x4 v = *reinterpret_cast<const f32x4*>(&emb[r*D_ + q*4]);
    a0 += v.x*mv; a1 += v.y*mv; a2 += v.z*mv; a3 += v.w*mv;
    cs += mv;
  }
  a0 += __shfl_xor(a0,16); a1 += __shfl_xor(a1,16); a2 += __shfl_xor(a2,16);
  a3 += __shfl_xor(a3,16); cs += __shfl_xor(cs,16);
  a0 += __shfl_xor(a0,32); a1 += __shfl_xor(a1,32); a2 += __shfl_xor(a2,32);
  a3 += __shfl_xor(a3,32); cs += __shfl_xor(cs,32);
  if (sub == 0){
    float inv = 1.f/(cs + 1.f);
    f32x4 w = {a0*inv, a1*inv, a2*inv, a3*inv};
    *reinterpret_cast<f32x4*>(&nf[(size_t)wid*NF_STRIDE + q*4]) = w;
  }
}

// ---- per-node Y GEMM: Ybuf[n][0:64]=W_row@nf+b, [64:128]=W_col@nf ----
__global__ __launch_bounds__(256) void k_ynode(
    const float* __restrict__ nf, const unsigned short* __restrict__ Wn,
    const float* __restrict__ bias, float* __restrict__ Ybuf, int Nn)
{
  __shared__ __align__(16) short tile[32*104];
  int tid = threadIdx.x;
  int n0 = blockIdx.x*32;
  if (tid < 128){
    int e = tid >> 2, w = tid & 3;
    *reinterpret_cast<short8*>(&tile[e*104 + 72 + w*8]) = short8{0,0,0,0,0,0,0,0};
  }
  const f32x4* nf4 = reinterpret_cast<const f32x4*>(nf);
  for (int s = tid; s < 32*18; s += 256){
    int e = s/18, q = s - e*18;
    f32x4 v = {0.f,0.f,0.f,0.f};
    if (n0 + e < Nn) v = nf4[(size_t)(n0+e)*18 + q];
    u32x2 pk;
    pk.x = f2bf(v.x) | (f2bf(v.y) << 16);
    pk.y = f2bf(v.z) | (f2bf(v.w) << 16);
    *reinterpret_cast<u32x2*>(&tile[e*104 + q*4]) = pk;
  }
  __syncthreads();
  int lane = tid & 63, wv = tid >> 6;
  int r16 = lane & 15, kg = lane >> 4;
  const short8* W8 = reinterpret_cast<const short8*>(Wn);
  f32x4 acc[2][2] = {};
  #pragma unroll
  for (int kc = 0; kc < 3; ++kc){
    short8 a0 = *reinterpret_cast<const short8*>(&tile[r16*104 + kc*32 + kg*8]);
    short8 a1 = *reinterpret_cast<const short8*>(&tile[(16+r16)*104 + kc*32 + kg*8]);
    #pragma unroll
    for (int t = 0; t < 2; ++t){
      int nt = wv*2 + t;
      short8 wf = W8[(nt*3 + kc)*64 + lane];
      acc[0][t] = __builtin_amdgcn_mfma_f32_16x16x32_bf16(a0, wf, acc[0][t], 0,0,0);
      acc[1][t] = __builtin_amdgcn_mfma_f32_16x16x32_bf16(a1, wf, acc[1][t], 0,0,0);
    }
  }
  #pragma unroll
  for (int t = 0; t < 2; ++t){
    int nt = wv*2 + t;
    int c = nt*16 + r16;
    float b = (nt < 4) ? bias[c] : 0.f;
    #pragma unroll
    for (int m = 0; m < 2; ++m)
      #pragma unroll
      for (int j = 0; j < 4; ++j){
        int node = n0 + m*16 + kg*4 + j;
        if (node < Nn) Ybuf[(size_t)node*128 + c] = acc[m][t][j] + b;
      }
  }
}

// ---- edge GEMM (CSR order): ea'[i] = relu(W_ea@ea[i] + Yrow[rowp[i]] + Ycol[colp[i]]) ----
template<int FIRST, int FOUT>
__global__ __launch_bounds__(256) void k_gemm(
    const unsigned short* __restrict__ ea_bf, const unsigned short* __restrict__ emb_bf,
    const float* __restrict__ Ybuf,
    unsigned short* __restrict__ ea_out_bf, float* __restrict__ ea_out_f32,
    const int* __restrict__ rowp, const int* __restrict__ colp,
    const int* __restrict__ relp, const int* __restrict__ csr,
    const unsigned short* __restrict__ Wea, int E)
{
  __shared__ __align__(16) float stile[EB*68];
  __shared__ int s_row[EB], s_col[EB], s_rel[EB], s_csr[EB];
  int tid = threadIdx.x;
  int e0 = blockIdx.x*EB;
  if (tid < EB){
    int ge = e0 + tid;
    bool ok = ge < E;
    s_row[tid] = ok ? rowp[ge] : 0;
    s_col[tid] = ok ? colp[ge] : 0;
    s_rel[tid] = (FIRST && ok) ? relp[ge] : 0;
    s_csr[tid] = (FOUT && ok) ? csr[ge] : 0;
  }
  __syncthreads();
  const f32x4* Yb4 = reinterpret_cast<const f32x4*>(Ybuf);
  f32x4* st4 = reinterpret_cast<f32x4*>(stile);
  #pragma unroll
  for (int h = 0; h < 4; ++h){
    int s = tid + h*256;
    int e = s >> 4, q = s & 15;
    f32x4 a = Yb4[(size_t)s_row[e]*32 + q];
    f32x4 b = Yb4[(size_t)s_col[e]*32 + 16 + q];
    st4[e*17 + q] = a + b;
  }
  int lane = tid & 63, wv = tid >> 6;
  int r16 = lane & 15, kg = lane >> 4;
  const short8* W8 = reinterpret_cast<const short8*>(Wea);
  short8 wf[4][2];
  #pragma unroll
  for (int nt = 0; nt < 4; ++nt)
    #pragma unroll
    for (int kc = 0; kc < 2; ++kc)
      wf[nt][kc] = W8[(nt*2 + kc)*64 + lane];
  f32x4 acc[4] = {};
  #pragma unroll
  for (int kc = 0; kc < 2; ++kc){
    short8 a;
    if (FIRST){
      a = *reinterpret_cast<const short8*>(&emb_bf[(size_t)s_rel[wv*16 + r16]*D_ + kc*32 + kg*8]);
    } else {
      int eA = e0 + wv*16 + r16; if (eA >= E) eA = E-1;
      a = *reinterpret_cast<const short8*>(&ea_bf[(size_t)eA*D_ + kc*32 + kg*8]);
    }
    #pragma unroll
    for (int nt = 0; nt < 4; ++nt)
      acc[nt] = __builtin_amdgcn_mfma_f32_16x16x32_bf16(a, wf[nt][kc], acc[nt], 0,0,0);
  }
  __syncthreads();   // stile staging complete before reads
  float v[4][4];
  #pragma unroll
  for (int nt = 0; nt < 4; ++nt)
    #pragma unroll
    for (int j = 0; j < 4; ++j){
      int et = wv*16 + kg*4 + j;           // C/D: row=(lane>>4)*4+j, col=lane&15
      float x = acc[nt][j] + stile[et*68 + nt*16 + r16];
      v[nt][j] = x > 0.f ? x : 0.f;
    }
  __syncthreads();
  if (FOUT == 0){
    unsigned short* ob = reinterpret_cast<unsigned short*>(stile);  // [64][72]
    #pragma unroll
    for (int nt = 0; nt < 4; ++nt)
      #pragma unroll
      for (int j = 0; j < 4; ++j)
        ob[(wv*16 + kg*4 + j)*72 + nt*16 + r16] = (unsigned short)f2bf(v[nt][j]);
    __syncthreads();
    #pragma unroll
    for (int h = 0; h < 2; ++h){
      int s = tid + h*256;
      int e = s >> 3, w = s & 7;
      int ge = e0 + e;
      if (ge < E)
        *reinterpret_cast<short8*>(&ea_out_bf[(size_t)ge*D_ + w*8]) =
          *reinterpret_cast<const short8*>(&ob[e*72 + w*8]);
    }
  } else {
    #pragma unroll
    for (int nt = 0; nt < 4; ++nt)
      #pragma unroll
      for (int j = 0; j < 4; ++j)
        stile[(wv*16 + kg*4 + j)*68 + nt*16 + r16] = v[nt][j];
    __syncthreads();
    f32x4* out4 = reinterpret_cast<f32x4*>(ea_out_f32);
    #pragma unroll
    for (int h = 0; h < 4; ++h){
      int s = tid + h*256;
      int e = s >> 4, q = s & 15;
      int ge = e0 + e;
      if (ge < E){
        f32x4 w = st4[e*17 + q];
        out4[(size_t)s_csr[e]*16 + q] = w;                 // f32 scatter to original order
        u32x2 pk;
        pk.x = f2bf(w.x) | (f2bf(w.y) << 16);
        pk.y = f2bf(w.z) | (f2bf(w.w) << 16);
        *reinterpret_cast<u32x2*>(&ea_out_bf[(size_t)ge*D_ + q*4]) = pk;  // bf16 seq for final agg
      }
    }
  }
}

__global__ void k_pool(const float* __restrict__ nrep_out, const int* __restrict__ head,
                       const int* __restrict__ counts, float* __restrict__ gout, int B){
  __shared__ float s[4][64];
  int g = blockIdx.x;
  int lane = threadIdx.x & 63, sub = threadIdx.x >> 6;
  int h = head[g]; int n = counts[g];
  float m = -3.402823466e38f;
  for (int i = sub; i < n; i += 4)
    m = fmaxf(m, nrep_out[(size_t)(h+i)*D_ + lane]);
  s[sub][lane] = m;
  __syncthreads();
  if (sub == 0){
    m = fmaxf(fmaxf(s[0][lane], s[1][lane]), fmaxf(s[2][lane], s[3][lane]));
    gout[(size_t)g*192 + lane]       = m;
    gout[(size_t)g*192 + 64  + lane] = nrep_out[(size_t)h*D_ + lane];
    gout[(size_t)g*192 + 128 + lane] = nrep_out[(size_t)(h+1)*D_ + lane];
  }
}

extern "C" void kernel_launch(void* const* d_in, const int* in_sizes, int n_in,
                              void* d_out, int out_size, void* d_ws, size_t ws_size,
                              hipStream_t stream)
{
  const float* x    = (const float*)d_in[0];
  const int*   eidx = (const int*)d_in[1];
  const int*   erel = (const int*)d_in[2];
  const int*   batch= (const int*)d_in[3];
  const float* mask = (const float*)d_in[4];
  const float* emb  = (const float*)d_in[5];
  const float* W0   = (const float*)d_in[6];
  const float* b0   = (const float*)d_in[7];
  const float* W1   = (const float*)d_in[8];
  const float* b1   = (const float*)d_in[9];
  const float* W2   = (const float*)d_in[10];
  const float* b2   = (const float*)d_in[11];

  int N = in_sizes[0] / NODE_DIM_;
  int E = in_sizes[2];
  int B = (int)(((long long)out_size - (long long)N*D_ - (long long)E*D_) / 192);

  float* out_ge   = (float*)d_out;                 // B*192
  float* out_nrep = out_ge + (size_t)B*192;        // N*64
  float* out_ea   = out_nrep + (size_t)N*D_;       // E*64  (f32, original edge order)

  char* w = (char*)d_ws;
  auto alloc = [&](size_t bytes)->char*{ char* p = w; w += (bytes + 255) & ~(size_t)255; return p; };
  unsigned short* ea_p = (unsigned short*)alloc((size_t)E*D_*2);    // 102.4 MB (CSR order)
  float* nf     = (float*)alloc((size_t)N*NF_STRIDE*4);             // 14.4 MB
  float* Ybuf   = (float*)alloc((size_t)N*128*4);                   // 25.6 MB
  int*   cnt_i  = (int*)  alloc((size_t)N*4);
  int*   off    = (int*)  alloc((size_t)(N+1)*4);
  int*   fpos   = (int*)  alloc((size_t)N*4);
  int*   csr    = (int*)  alloc((size_t)E*4);
  int*   rowp   = (int*)  alloc((size_t)E*4);
  int*   colp   = (int*)  alloc((size_t)E*4);
  int*   relp   = (int*)  alloc((size_t)E*4);
  float* maskp  = (float*)alloc((size_t)E*4);
  int*   counts = (int*)  alloc((size_t)B*4);
  int*   head   = (int*)  alloc((size_t)B*4);
  unsigned short* Wea = (unsigned short*)alloc((size_t)3*WEA_PER_LAYER*2);
  unsigned short* Wn  = (unsigned short*)alloc((size_t)3*WN_PER_LAYER*2);
  unsigned short* emb_bf = (unsigned short*)alloc((size_t)200*D_*2 + 256);

  hipMemsetAsync(nf,     0, (size_t)N*NF_STRIDE*4, stream);
  hipMemsetAsync(cnt_i,  0, (size_t)N*4, stream);
  hipMemsetAsync(fpos,   0, (size_t)N*4, stream);
  hipMemsetAsync(counts, 0, (size_t)B*4, stream);

  const int* erow = eidx;
  const int* ecol = eidx + E;

  k_count_batch<<<(N+255)/256, 256, 0, stream>>>(batch, counts, N);
  k_scan_heads <<<1, 1024, 0, stream>>>(counts, head, B);
  k_x0         <<<(B*2*NODE_DIM_+255)/256, 256, 0, stream>>>(head, x, nf, B);
  k_cnt_int    <<<(E+255)/256, 256, 0, stream>>>(ecol, cnt_i, E);
  k_scan_off   <<<1, 1024, 0, stream>>>(cnt_i, off, N);
  k_fill       <<<(E+255)/256, 256, 0, stream>>>(erow, ecol, erel, mask, off, fpos,
                                                 csr, rowp, colp, relp, maskp, E);
  k_pack_w     <<<(3*(WEA_PER_LAYER+WN_PER_LAYER)+255)/256, 256, 0, stream>>>(W0, W1, W2, Wea, Wn);
  k_pack_emb   <<<(200*D_+255)/256, 256, 0, stream>>>(emb, emb_bf, 200*D_);

  int nblk_g = (E + EB - 1) / EB;
  int nblk_a = (N + 3) / 4;
  int nblk_y = (N + 31) / 32;

  // layer 0
  k_agg0_seq<<<nblk_a, 256, 0, stream>>>(emb, relp, off, maskp, nf, N);
  k_ynode<<<nblk_y, 256, 0, stream>>>(nf, Wn, b0, Ybuf, N);
  k_gemm<1,0><<<nblk_g, 256, 0, stream>>>(ea_p, emb_bf, Ybuf, ea_p, out_ea,
                                          rowp, colp, relp, csr, Wea, E);
  // layer 1
  k_agg_seq<<<nblk_a, 256, 0, stream>>>(ea_p, off, maskp, nf, NF_STRIDE, N);
  k_ynode<<<nblk_y, 256, 0, stream>>>(nf, Wn + WN_PER_LAYER, b1, Ybuf, N);
  k_gemm<0,0><<<nblk_g, 256, 0, stream>>>(ea_p, emb_bf, Ybuf, ea_p, out_ea,
                                          rowp, colp, relp, csr, Wea + WEA_PER_LAYER, E);
  // layer 2 (dual write: bf16 seq + f32 scatter to d_out)
  k_agg_seq<<<nblk_a, 256, 0, stream>>>(ea_p, off, maskp, nf, NF_STRIDE, N);
  k_ynode<<<nblk_y, 256, 0, stream>>>(nf, Wn + 2*WN_PER_LAYER, b2, Ybuf, N);
  k_gemm<0,1><<<nblk_g, 256, 0, stream>>>(ea_p, emb_bf, Ybuf, ea_p, out_ea,
                                          rowp, colp, relp, csr, Wea + 2*WEA_PER_LAYER, E);

  k_agg_seq<<<nblk_a, 256, 0, stream>>>(ea_p, off, maskp, out_nrep, D_, N);
  k_pool<<<B, 256, 0, stream>>>(out_nrep, head, counts, out_ge, B);
}

// Round 6
// 785.084 us; speedup vs baseline: 2.1738x; 1.0544x over previous
//
#include <hip/hip_runtime.h>
#include <stdint.h>

typedef __attribute__((ext_vector_type(8))) short short8;
typedef __attribute__((ext_vector_type(4))) float f32x4;
typedef __attribute__((ext_vector_type(2))) unsigned int u32x2;

#define D_ 64
#define NODE_DIM_ 6
#define INF_ 204          // IN_FEAT = 3*64 + 2*6
#define EB 64             // edges per GEMM block
#define WEA_PER_LAYER 4096    // 4nt*2kc*64lane*8
#define WN_PER_LAYER 12288    // 8nt*3kc*64lane*8

__device__ __forceinline__ unsigned int f2bf(float f){
  uint32_t u = __float_as_uint(f);
  u += 0x7fffu + ((u >> 16) & 1u);   // RNE (finite values only)
  return u >> 16;
}

// merged: batch-count (N) + col-count (E)
__global__ void k_counts(const int* __restrict__ batch, const int* __restrict__ col,
                         int* __restrict__ counts, int* __restrict__ cnt, int N, int E){
  int i = blockIdx.x*256 + threadIdx.x;
  if (i < E) atomicAdd(&cnt[col[i]], 1);
  if (i < N) atomicAdd(&counts[batch[i]], 1);
}

// merged: CSR offset scan (N+1) + head-index scan (B)
__global__ void k_scans(const int* __restrict__ cnt, int* __restrict__ off, int Nn,
                        const int* __restrict__ counts, int* __restrict__ head, int B){
  __shared__ int s[1024];
  int t = threadIdx.x;
  const int CH = (Nn + 1024) / 1024;
  int base = t*CH;
  int sum = 0;
  for (int i = 0; i < CH; ++i){ int idx = base+i; if (idx < Nn) sum += cnt[idx]; }
  s[t] = sum;
  __syncthreads();
  for (int o = 1; o < 1024; o <<= 1){
    int u = (t >= o) ? s[t-o] : 0;
    __syncthreads();
    s[t] += u;
    __syncthreads();
  }
  int run = (t == 0) ? 0 : s[t-1];
  for (int i = 0; i < CH; ++i){
    int idx = base+i;
    if (idx <= Nn){ off[idx] = run; if (idx < Nn) run += cnt[idx]; }
  }
  __syncthreads();
  // phase 2: head indices
  int v = (t < B) ? counts[t] : 0;
  s[t] = v;
  __syncthreads();
  for (int o = 1; o < 1024; o <<= 1){
    int u = (t >= o) ? s[t-o] : 0;
    __syncthreads();
    s[t] += u;
    __syncthreads();
  }
  if (t < B) head[t] = s[t] - v;
}

// scatter edge data into CSR order
__global__ void k_fill(const int* __restrict__ row, const int* __restrict__ col,
                       const int* __restrict__ rel, const float* __restrict__ mask,
                       const int* __restrict__ off, int* __restrict__ fpos,
                       int* __restrict__ csr, int* __restrict__ rowp, int* __restrict__ colp,
                       int* __restrict__ relp, float* __restrict__ maskp, int E){
  int e = blockIdx.x*256 + threadIdx.x;
  if (e >= E) return;
  int c = col[e];
  int p = atomicAdd(&fpos[c], 1);
  int pos = off[c] + p;
  csr[pos]  = e;
  rowp[pos] = row[e];
  colp[pos] = c;
  relp[pos] = rel[e];
  maskp[pos]= mask[e];
}

// x0 (head/tail rows of x) -> x0buf[node][0:6] (rest stays zero)
__global__ void k_x0b(const int* __restrict__ head, const float* __restrict__ x,
                      float* __restrict__ x0b, int B){
  int idx = blockIdx.x*256 + threadIdx.x;
  if (idx >= B*2*NODE_DIM_) return;
  int g = idx / (2*NODE_DIM_);
  int j = idx % (2*NODE_DIM_);
  int node = head[g] + j / NODE_DIM_;
  int c = j % NODE_DIM_;
  x0b[(size_t)node*8 + c] = x[node*NODE_DIM_ + c];
}

// pack W_ea (c, 140+k) and W_node (Yrow: c,k | Ycol: c-64, 70+k) into MFMA B-frag order
__global__ void k_pack_w(const float* __restrict__ W0, const float* __restrict__ W1,
                         const float* __restrict__ W2,
                         unsigned short* __restrict__ Wea, unsigned short* __restrict__ Wn){
  int idx = blockIdx.x*256 + threadIdx.x;
  if (idx < 3*WEA_PER_LAYER){
    int l = idx / WEA_PER_LAYER;
    int rem = idx % WEA_PER_LAYER;
    const float* W = (l==0) ? W0 : ((l==1) ? W1 : W2);
    int i = rem & 7, s = rem >> 3;
    int lane = s & 63, t = s >> 6;          // t = nt*2 + kc
    int kc = t & 1, nt = t >> 1;
    int n = lane & 15, kg = lane >> 4;
    int k = kc*32 + kg*8 + i;               // 0..63
    int c = nt*16 + n;                      // 0..63
    Wea[idx] = (unsigned short)f2bf(W[c*INF_ + 140 + k]);
    return;
  }
  int idx2 = idx - 3*WEA_PER_LAYER;
  if (idx2 >= 3*WN_PER_LAYER) return;
  int l = idx2 / WN_PER_LAYER;
  int rem = idx2 % WN_PER_LAYER;
  const float* W = (l==0) ? W0 : ((l==1) ? W1 : W2);
  int i = rem & 7, s = rem >> 3;
  int lane = s & 63, t = s >> 6;            // t = nt*3 + kc
  int kc = t % 3, nt = t / 3;               // nt 0..7
  int n = lane & 15, kg = lane >> 4;
  int k = kc*32 + kg*8 + i;                 // 0..95
  int c = nt*16 + n;                        // 0..127
  float v = 0.f;
  if (k < 70) v = (nt < 4) ? W[c*INF_ + k] : W[(c-64)*INF_ + 70 + k];
  Wn[idx2] = (unsigned short)f2bf(v);
}

__global__ void k_pack_emb(const float* __restrict__ emb, unsigned short* __restrict__ emb_bf, int n){
  int i = blockIdx.x*256 + threadIdx.x;
  if (i < n) emb_bf[i] = (unsigned short)f2bf(emb[i]);
}

// layer-0 aggregation: divided sums -> agg (stride 64), and inv[n]=1/(cs+1) (layer-invariant)
__global__ __launch_bounds__(256) void k_agg0_inv(
    const float* __restrict__ emb, const int* __restrict__ relp,
    const int* __restrict__ off, const float* __restrict__ maskp,
    float* __restrict__ agg, float* __restrict__ inv, int Nn)
{
  int wid = (blockIdx.x*256 + threadIdx.x) >> 6;
  if (wid >= Nn) return;
  int lane = threadIdx.x & 63;
  int sub = lane >> 4, q = lane & 15;
  int s = off[wid], t = off[wid+1];
  float a0=0.f,a1=0.f,a2=0.f,a3=0.f, cs=0.f;
  for (int i = s; i < t; i += 4){
    int ii = i + sub;
    float mv = (ii < t) ? maskp[ii] : 0.f;
    int r = (ii < t) ? relp[ii] : 0;
    f32x4 v = *reinterpret_cast<const f32x4*>(&emb[r*D_ + q*4]);
    a0 += v.x*mv; a1 += v.y*mv; a2 += v.z*mv; a3 += v.w*mv;
    cs += mv;
  }
  a0 += __shfl_xor(a0,16); a1 += __shfl_xor(a1,16); a2 += __shfl_xor(a2,16);
  a3 += __shfl_xor(a3,16); cs += __shfl_xor(cs,16);
  a0 += __shfl_xor(a0,32); a1 += __shfl_xor(a1,32); a2 += __shfl_xor(a2,32);
  a3 += __shfl_xor(a3,32); cs += __shfl_xor(cs,32);
  if (sub == 0){
    float iv = 1.f/(cs + 1.f);
    f32x4 w = {a0*iv, a1*iv, a2*iv, a3*iv};
    *reinterpret_cast<f32x4*>(&agg[(size_t)wid*D_ + q*4]) = w;
    if (q == 0) inv[wid] = iv;
  }
}

// ---- per-node Y GEMM: Ybuf[n][0:64]=W_row@[agg|x0]+b, [64:128]=W_col@[agg|x0] ----
__global__ __launch_bounds__(256) void k_ynode(
    const float* __restrict__ agg, const float* __restrict__ x0b,
    const unsigned short* __restrict__ Wn,
    const float* __restrict__ bias, float* __restrict__ Ybuf, int Nn)
{
  __shared__ __align__(16) short tile[32*104];
  int tid = threadIdx.x;
  int n0 = blockIdx.x*32;
  if (tid < 128){
    int e = tid >> 2, w = tid & 3;
    *reinterpret_cast<short8*>(&tile[e*104 + 72 + w*8]) = short8{0,0,0,0,0,0,0,0};
  }
  const f32x4* agg4 = reinterpret_cast<const f32x4*>(agg);
  const f32x4* x0b4 = reinterpret_cast<const f32x4*>(x0b);
  for (int s = tid; s < 32*18; s += 256){
    int e = s/18, q = s - e*18;
    f32x4 v = {0.f,0.f,0.f,0.f};
    if (n0 + e < Nn){
      if (q < 16) v = agg4[(size_t)(n0+e)*16 + q];
      else        v = x0b4[(size_t)(n0+e)*2 + (q-16)];
    }
    u32x2 pk;
    pk.x = f2bf(v.x) | (f2bf(v.y) << 16);
    pk.y = f2bf(v.z) | (f2bf(v.w) << 16);
    *reinterpret_cast<u32x2*>(&tile[e*104 + q*4]) = pk;
  }
  __syncthreads();
  int lane = tid & 63, wv = tid >> 6;
  int r16 = lane & 15, kg = lane >> 4;
  const short8* W8 = reinterpret_cast<const short8*>(Wn);
  f32x4 acc[2][2] = {};
  #pragma unroll
  for (int kc = 0; kc < 3; ++kc){
    short8 a0 = *reinterpret_cast<const short8*>(&tile[r16*104 + kc*32 + kg*8]);
    short8 a1 = *reinterpret_cast<const short8*>(&tile[(16+r16)*104 + kc*32 + kg*8]);
    #pragma unroll
    for (int t = 0; t < 2; ++t){
      int nt = wv*2 + t;
      short8 wf = W8[(nt*3 + kc)*64 + lane];
      acc[0][t] = __builtin_amdgcn_mfma_f32_16x16x32_bf16(a0, wf, acc[0][t], 0,0,0);
      acc[1][t] = __builtin_amdgcn_mfma_f32_16x16x32_bf16(a1, wf, acc[1][t], 0,0,0);
    }
  }
  #pragma unroll
  for (int t = 0; t < 2; ++t){
    int nt = wv*2 + t;
    int c = nt*16 + r16;
    float b = (nt < 4) ? bias[c] : 0.f;
    #pragma unroll
    for (int m = 0; m < 2; ++m)
      #pragma unroll
      for (int j = 0; j < 4; ++j){
        int node = n0 + m*16 + kg*4 + j;
        if (node < Nn) Ybuf[(size_t)node*128 + c] = acc[m][t][j] + b;
      }
  }
}

// ---- edge GEMM (CSR order) with fused segmented-reduction aggregation ----
// ea'[i] = relu(W_ea@ea[i] + Yrow[rowp[i]] + Ycol[colp[i]]);  agg[col] += ea'*mask*inv[col]
template<int FIRST, int FOUT>
__global__ __launch_bounds__(256) void k_gemm(
    const unsigned short* __restrict__ ea_bf, const unsigned short* __restrict__ emb_bf,
    const float* __restrict__ Ybuf,
    unsigned short* __restrict__ ea_out_bf, float* __restrict__ ea_out_f32,
    float* __restrict__ agg,
    const int* __restrict__ rowp, const int* __restrict__ colp,
    const int* __restrict__ relp, const int* __restrict__ csr,
    const float* __restrict__ maskp, const float* __restrict__ inv,
    const unsigned short* __restrict__ Wea, int E)
{
  __shared__ __align__(16) float stile[EB*68];
  __shared__ int s_row[EB], s_col[EB], s_rel[EB], s_csr[EB];
  __shared__ float s_mask[EB], s_inv[EB];
  int tid = threadIdx.x;
  int e0 = blockIdx.x*EB;
  if (tid < EB){
    int ge = e0 + tid;
    bool ok = ge < E;
    int cc = ok ? colp[ge] : 0;
    s_col[tid] = cc;
    s_row[tid] = ok ? rowp[ge] : 0;
    s_mask[tid]= ok ? maskp[ge] : 0.f;
    s_inv[tid] = inv[cc];
    if (FIRST) s_rel[tid] = ok ? relp[ge] : 0;
    if (FOUT)  s_csr[tid] = ok ? csr[ge] : 0;
  }
  __syncthreads();
  const f32x4* Yb4 = reinterpret_cast<const f32x4*>(Ybuf);
  f32x4* st4 = reinterpret_cast<f32x4*>(stile);
  #pragma unroll
  for (int h = 0; h < 4; ++h){
    int s = tid + h*256;
    int e = s >> 4, q = s & 15;
    f32x4 a = Yb4[(size_t)s_row[e]*32 + q];
    f32x4 b = Yb4[(size_t)s_col[e]*32 + 16 + q];
    st4[e*17 + q] = a + b;
  }
  int lane = tid & 63, wv = tid >> 6;
  int r16 = lane & 15, kg = lane >> 4;
  const short8* W8 = reinterpret_cast<const short8*>(Wea);
  short8 wf[4][2];
  #pragma unroll
  for (int nt = 0; nt < 4; ++nt)
    #pragma unroll
    for (int kc = 0; kc < 2; ++kc)
      wf[nt][kc] = W8[(nt*2 + kc)*64 + lane];
  f32x4 acc[4] = {};
  #pragma unroll
  for (int kc = 0; kc < 2; ++kc){
    short8 a;
    if (FIRST){
      a = *reinterpret_cast<const short8*>(&emb_bf[(size_t)s_rel[wv*16 + r16]*D_ + kc*32 + kg*8]);
    } else {
      int eA = e0 + wv*16 + r16; if (eA >= E) eA = E-1;
      a = *reinterpret_cast<const short8*>(&ea_bf[(size_t)eA*D_ + kc*32 + kg*8]);
    }
    #pragma unroll
    for (int nt = 0; nt < 4; ++nt)
      acc[nt] = __builtin_amdgcn_mfma_f32_16x16x32_bf16(a, wf[nt][kc], acc[nt], 0,0,0);
  }
  __syncthreads();   // stile Y staging complete before reads
  float v[4][4];
  #pragma unroll
  for (int nt = 0; nt < 4; ++nt)
    #pragma unroll
    for (int j = 0; j < 4; ++j){
      int et = wv*16 + kg*4 + j;           // C/D: row=(lane>>4)*4+j, col=lane&15
      float x = acc[nt][j] + stile[et*68 + nt*16 + r16];
      v[nt][j] = x > 0.f ? x : 0.f;
    }
  __syncthreads();
  if (FOUT == 0){
    unsigned short* ob = reinterpret_cast<unsigned short*>(stile);  // bf16 [64][72]
    #pragma unroll
    for (int nt = 0; nt < 4; ++nt)
      #pragma unroll
      for (int j = 0; j < 4; ++j)
        ob[(wv*16 + kg*4 + j)*72 + nt*16 + r16] = (unsigned short)f2bf(v[nt][j]);
    __syncthreads();
    // coalesced bf16 store (next layer's GEMM input)
    #pragma unroll
    for (int h = 0; h < 2; ++h){
      int s = tid + h*256;
      int e = s >> 3, w = s & 7;
      int ge = e0 + e;
      if (ge < E)
        *reinterpret_cast<short8*>(&ea_out_bf[(size_t)ge*D_ + w*8]) =
          *reinterpret_cast<const short8*>(&ob[e*72 + w*8]);
    }
    // fused segmented reduction: wave-uniform runs, coalesced atomic bursts
    {
      int c = tid & 63, g = tid >> 6;
      int base = g*16;
      int cur = s_col[base]; float civ = s_inv[base]; float run = 0.f;
      #pragma unroll
      for (int e = base; e < base+16; ++e){
        int col = s_col[e];
        if (col != cur){
          atomicAdd(&agg[(size_t)cur*D_ + c], run*civ);
          run = 0.f; cur = col; civ = s_inv[e];
        }
        float val = __uint_as_float((uint32_t)ob[e*72 + c] << 16);
        run += val * s_mask[e];
      }
      atomicAdd(&agg[(size_t)cur*D_ + c], run*civ);
    }
  } else {
    #pragma unroll
    for (int nt = 0; nt < 4; ++nt)
      #pragma unroll
      for (int j = 0; j < 4; ++j)
        stile[(wv*16 + kg*4 + j)*68 + nt*16 + r16] = v[nt][j];
    __syncthreads();
    // f32 scatter to original edge order (required output)
    f32x4* out4 = reinterpret_cast<f32x4*>(ea_out_f32);
    #pragma unroll
    for (int h = 0; h < 4; ++h){
      int s = tid + h*256;
      int e = s >> 4, q = s & 15;
      int ge = e0 + e;
      if (ge < E) out4[(size_t)s_csr[e]*16 + q] = st4[e*17 + q];
    }
    // fused segmented reduction (f32 source) -> out_nrep (pre-zeroed)
    {
      int c = tid & 63, g = tid >> 6;
      int base = g*16;
      int cur = s_col[base]; float civ = s_inv[base]; float run = 0.f;
      #pragma unroll
      for (int e = base; e < base+16; ++e){
        int col = s_col[e];
        if (col != cur){
          atomicAdd(&agg[(size_t)cur*D_ + c], run*civ);
          run = 0.f; cur = col; civ = s_inv[e];
        }
        run += stile[e*68 + c] * s_mask[e];
      }
      atomicAdd(&agg[(size_t)cur*D_ + c], run*civ);
    }
  }
}

__global__ void k_pool(const float* __restrict__ nrep_out, const int* __restrict__ head,
                       const int* __restrict__ counts, float* __restrict__ gout, int B){
  __shared__ float s[4][64];
  int g = blockIdx.x;
  int lane = threadIdx.x & 63, sub = threadIdx.x >> 6;
  int h = head[g]; int n = counts[g];
  float m = -3.402823466e38f;
  for (int i = sub; i < n; i += 4)
    m = fmaxf(m, nrep_out[(size_t)(h+i)*D_ + lane]);
  s[sub][lane] = m;
  __syncthreads();
  if (sub == 0){
    m = fmaxf(fmaxf(s[0][lane], s[1][lane]), fmaxf(s[2][lane], s[3][lane]));
    gout[(size_t)g*192 + lane]       = m;
    gout[(size_t)g*192 + 64  + lane] = nrep_out[(size_t)h*D_ + lane];
    gout[(size_t)g*192 + 128 + lane] = nrep_out[(size_t)(h+1)*D_ + lane];
  }
}

extern "C" void kernel_launch(void* const* d_in, const int* in_sizes, int n_in,
                              void* d_out, int out_size, void* d_ws, size_t ws_size,
                              hipStream_t stream)
{
  const float* x    = (const float*)d_in[0];
  const int*   eidx = (const int*)d_in[1];
  const int*   erel = (const int*)d_in[2];
  const int*   batch= (const int*)d_in[3];
  const float* mask = (const float*)d_in[4];
  const float* emb  = (const float*)d_in[5];
  const float* W0   = (const float*)d_in[6];
  const float* b0   = (const float*)d_in[7];
  const float* W1   = (const float*)d_in[8];
  const float* b1   = (const float*)d_in[9];
  const float* W2   = (const float*)d_in[10];
  const float* b2   = (const float*)d_in[11];

  int N = in_sizes[0] / NODE_DIM_;
  int E = in_sizes[2];
  int B = (int)(((long long)out_size - (long long)N*D_ - (long long)E*D_) / 192);

  float* out_ge   = (float*)d_out;                 // B*192
  float* out_nrep = out_ge + (size_t)B*192;        // N*64  (atomic target of layer-2 gemm)
  float* out_ea   = out_nrep + (size_t)N*D_;       // E*64  (f32, original edge order)

  char* w = (char*)d_ws;
  auto alloc = [&](size_t bytes)->char*{ char* p = w; w += (bytes + 255) & ~(size_t)255; return p; };
  unsigned short* ea_p = (unsigned short*)alloc((size_t)E*D_*2);    // 102.4 MB (CSR order)
  float* Ybuf   = (float*)alloc((size_t)N*128*4);                   // 25.6 MB
  float* aggP   = (float*)alloc((size_t)N*D_*4);                    // 12.8 MB
  float* aggQ   = (float*)alloc((size_t)N*D_*4);                    // 12.8 MB
  float* x0b    = (float*)alloc((size_t)N*8*4);                     // 1.6 MB
  float* invb   = (float*)alloc((size_t)N*4);
  int*   cnt_i  = (int*)  alloc((size_t)N*4);
  int*   off    = (int*)  alloc((size_t)(N+1)*4);
  int*   fpos   = (int*)  alloc((size_t)N*4);
  int*   csr    = (int*)  alloc((size_t)E*4);
  int*   rowp   = (int*)  alloc((size_t)E*4);
  int*   colp   = (int*)  alloc((size_t)E*4);
  int*   relp   = (int*)  alloc((size_t)E*4);
  float* maskp  = (float*)alloc((size_t)E*4);
  int*   counts = (int*)  alloc((size_t)B*4);
  int*   head   = (int*)  alloc((size_t)B*4);
  unsigned short* Wea = (unsigned short*)alloc((size_t)3*WEA_PER_LAYER*2);
  unsigned short* Wn  = (unsigned short*)alloc((size_t)3*WN_PER_LAYER*2);
  unsigned short* emb_bf = (unsigned short*)alloc((size_t)200*D_*2 + 256);

  hipMemsetAsync(cnt_i,  0, (size_t)N*4, stream);
  hipMemsetAsync(fpos,   0, (size_t)N*4, stream);
  hipMemsetAsync(counts, 0, (size_t)B*4, stream);
  hipMemsetAsync(x0b,    0, (size_t)N*8*4, stream);
  hipMemsetAsync(aggQ,   0, (size_t)N*D_*4, stream);   // gemm0 atomic target

  const int* erow = eidx;
  const int* ecol = eidx + E;

  k_counts   <<<(E+255)/256, 256, 0, stream>>>(batch, ecol, counts, cnt_i, N, E);
  k_scans    <<<1, 1024, 0, stream>>>(cnt_i, off, N, counts, head, B);
  k_x0b      <<<(B*2*NODE_DIM_+255)/256, 256, 0, stream>>>(head, x, x0b, B);
  k_fill     <<<(E+255)/256, 256, 0, stream>>>(erow, ecol, erel, mask, off, fpos,
                                               csr, rowp, colp, relp, maskp, E);
  k_pack_w   <<<(3*(WEA_PER_LAYER+WN_PER_LAYER)+255)/256, 256, 0, stream>>>(W0, W1, W2, Wea, Wn);
  k_pack_emb <<<(200*D_+255)/256, 256, 0, stream>>>(emb, emb_bf, 200*D_);

  int nblk_g = (E + EB - 1) / EB;
  int nblk_a = (N + 3) / 4;
  int nblk_y = (N + 31) / 32;

  // layer 0: agg0 (divided sums + inv) -> ynode -> gemm (atomics into aggQ)
  k_agg0_inv<<<nblk_a, 256, 0, stream>>>(emb, relp, off, maskp, aggP, invb, N);
  k_ynode<<<nblk_y, 256, 0, stream>>>(aggP, x0b, Wn, b0, Ybuf, N);
  k_gemm<1,0><<<nblk_g, 256, 0, stream>>>(ea_p, emb_bf, Ybuf, ea_p, out_ea, aggQ,
                                          rowp, colp, relp, csr, maskp, invb, Wea, E);
  // layer 1: gemm atomics into aggP (re-zeroed after ynode0 consumed it)
  hipMemsetAsync(aggP, 0, (size_t)N*D_*4, stream);
  k_ynode<<<nblk_y, 256, 0, stream>>>(aggQ, x0b, Wn + WN_PER_LAYER, b1, Ybuf, N);
  k_gemm<0,0><<<nblk_g, 256, 0, stream>>>(ea_p, emb_bf, Ybuf, ea_p, out_ea, aggP,
                                          rowp, colp, relp, csr, maskp, invb,
                                          Wea + WEA_PER_LAYER, E);
  // layer 2: f32 scatter to d_out + atomics directly into out_nrep
  hipMemsetAsync(out_nrep, 0, (size_t)N*D_*4, stream);
  k_ynode<<<nblk_y, 256, 0, stream>>>(aggP, x0b, Wn + 2*WN_PER_LAYER, b2, Ybuf, N);
  k_gemm<0,1><<<nblk_g, 256, 0, stream>>>(ea_p, emb_bf, Ybuf, ea_p, out_ea, out_nrep,
                                          rowp, colp, relp, csr, maskp, invb,
                                          Wea + 2*WEA_PER_LAYER, E);

  k_pool<<<B, 256, 0, stream>>>(out_nrep, head, counts, out_ge, B);
}

// Round 7
// 733.617 us; speedup vs baseline: 2.3263x; 1.0702x over previous
//
#include <hip/hip_runtime.h>
#include <stdint.h>

typedef __attribute__((ext_vector_type(8))) short short8;
typedef __attribute__((ext_vector_type(4))) float f32x4;
typedef __attribute__((ext_vector_type(2))) unsigned int u32x2;

#define D_ 64
#define NODE_DIM_ 6
#define INF_ 204          // IN_FEAT = 3*64 + 2*6
#define EB 64             // edges per GEMM block
#define WEA_PER_LAYER 4096    // 4nt*2kc*64lane*8
#define WN_PER_LAYER 12288    // 8nt*3kc*64lane*8

__device__ __forceinline__ unsigned int f2bf(float f){
  uint32_t u = __float_as_uint(f);
  u += 0x7fffu + ((u >> 16) & 1u);   // RNE (finite values only)
  return u >> 16;
}

// merged: batch-count (N) + col-count (E)
__global__ void k_counts(const int* __restrict__ batch, const int* __restrict__ col,
                         int* __restrict__ counts, int* __restrict__ cnt, int N, int E){
  int i = blockIdx.x*256 + threadIdx.x;
  if (i < E) atomicAdd(&cnt[col[i]], 1);
  if (i < N) atomicAdd(&counts[batch[i]], 1);
}

// merged: CSR offset scan (N+1) + head-index scan (B) + x0 gather
__global__ void k_scans(const int* __restrict__ cnt, int* __restrict__ off, int Nn,
                        const int* __restrict__ counts, int* __restrict__ head, int B,
                        const float* __restrict__ x, float* __restrict__ x0b){
  __shared__ int s[1024];
  int t = threadIdx.x;
  const int CH = (Nn + 1024) / 1024;
  int base = t*CH;
  int sum = 0;
  for (int i = 0; i < CH; ++i){ int idx = base+i; if (idx < Nn) sum += cnt[idx]; }
  s[t] = sum;
  __syncthreads();
  for (int o = 1; o < 1024; o <<= 1){
    int u = (t >= o) ? s[t-o] : 0;
    __syncthreads();
    s[t] += u;
    __syncthreads();
  }
  int run = (t == 0) ? 0 : s[t-1];
  for (int i = 0; i < CH; ++i){
    int idx = base+i;
    if (idx <= Nn){ off[idx] = run; if (idx < Nn) run += cnt[idx]; }
  }
  __syncthreads();
  // phase 2: head indices
  int v = (t < B) ? counts[t] : 0;
  s[t] = v;
  __syncthreads();
  for (int o = 1; o < 1024; o <<= 1){
    int u = (t >= o) ? s[t-o] : 0;
    __syncthreads();
    s[t] += u;
    __syncthreads();
  }
  if (t < B) head[t] = s[t] - v;
  __syncthreads();
  // phase 3: x0 gather (head/tail node features -> x0b[node][0:6])
  for (int idx = t; idx < B*2*NODE_DIM_; idx += 1024){
    int g = idx / (2*NODE_DIM_);
    int j = idx % (2*NODE_DIM_);
    int node = (s[g] - counts[g]) + j / NODE_DIM_;
    int c = j % NODE_DIM_;
    x0b[(size_t)node*8 + c] = x[node*NODE_DIM_ + c];
  }
}

// scatter edge data into CSR order: ONE 16B store per edge
// e4[pos] = {row, col, (orig_e<<8)|rel, mask_bits}
__global__ void k_fill(const int* __restrict__ row, const int* __restrict__ col,
                       const int* __restrict__ rel, const float* __restrict__ mask,
                       int* __restrict__ fpos, int4* __restrict__ e4, int E){
  int e = blockIdx.x*256 + threadIdx.x;
  if (e >= E) return;
  int c = col[e];
  int pos = atomicAdd(&fpos[c], 1);   // fpos pre-loaded with off[]
  e4[pos] = make_int4(row[e], c, (e << 8) | rel[e], __float_as_int(mask[e]));
}

// pack W_ea (c,140+k), W_node (Yrow: c,k | Ycol: c-64,70+k), and emb -> bf16
__global__ void k_pack(const float* __restrict__ W0, const float* __restrict__ W1,
                       const float* __restrict__ W2, const float* __restrict__ emb,
                       unsigned short* __restrict__ Wea, unsigned short* __restrict__ Wn,
                       unsigned short* __restrict__ emb_bf){
  int idx = blockIdx.x*256 + threadIdx.x;
  if (idx < 3*WEA_PER_LAYER){
    int l = idx / WEA_PER_LAYER;
    int rem = idx % WEA_PER_LAYER;
    const float* W = (l==0) ? W0 : ((l==1) ? W1 : W2);
    int i = rem & 7, s = rem >> 3;
    int lane = s & 63, t = s >> 6;          // t = nt*2 + kc
    int kc = t & 1, nt = t >> 1;
    int n = lane & 15, kg = lane >> 4;
    int k = kc*32 + kg*8 + i;               // 0..63
    int c = nt*16 + n;                      // 0..63
    Wea[idx] = (unsigned short)f2bf(W[c*INF_ + 140 + k]);
    return;
  }
  int idx2 = idx - 3*WEA_PER_LAYER;
  if (idx2 < 3*WN_PER_LAYER){
    int l = idx2 / WN_PER_LAYER;
    int rem = idx2 % WN_PER_LAYER;
    const float* W = (l==0) ? W0 : ((l==1) ? W1 : W2);
    int i = rem & 7, s = rem >> 3;
    int lane = s & 63, t = s >> 6;            // t = nt*3 + kc
    int kc = t % 3, nt = t / 3;               // nt 0..7
    int n = lane & 15, kg = lane >> 4;
    int k = kc*32 + kg*8 + i;                 // 0..95
    int c = nt*16 + n;                        // 0..127
    float v = 0.f;
    if (k < 70) v = (nt < 4) ? W[c*INF_ + k] : W[(c-64)*INF_ + 70 + k];
    Wn[idx2] = (unsigned short)f2bf(v);
    return;
  }
  int idx3 = idx2 - 3*WN_PER_LAYER;
  if (idx3 < 200*D_) emb_bf[idx3] = (unsigned short)f2bf(emb[idx3]);
}

// layer-0 aggregation: divided sums -> agg (stride 64), and inv[n]=1/(cs+1)
__global__ __launch_bounds__(256) void k_agg0_inv(
    const float* __restrict__ emb, const int4* __restrict__ e4,
    const int* __restrict__ off, float* __restrict__ agg,
    float* __restrict__ inv, int Nn)
{
  int wid = (blockIdx.x*256 + threadIdx.x) >> 6;
  if (wid >= Nn) return;
  int lane = threadIdx.x & 63;
  int sub = lane >> 4, ch = lane & 15;
  int s = off[wid], t = off[wid+1];
  float a0=0.f,a1=0.f,a2=0.f,a3=0.f, cs=0.f;
  for (int i = s; i < t; i += 4){
    int ii = i + sub;
    float mv = 0.f; int r = 0;
    if (ii < t){ int4 q = e4[ii]; r = q.z & 0xff; mv = __int_as_float(q.w); }
    f32x4 v = *reinterpret_cast<const f32x4*>(&emb[r*D_ + ch*4]);
    a0 += v.x*mv; a1 += v.y*mv; a2 += v.z*mv; a3 += v.w*mv;
    cs += mv;
  }
  a0 += __shfl_xor(a0,16); a1 += __shfl_xor(a1,16); a2 += __shfl_xor(a2,16);
  a3 += __shfl_xor(a3,16); cs += __shfl_xor(cs,16);
  a0 += __shfl_xor(a0,32); a1 += __shfl_xor(a1,32); a2 += __shfl_xor(a2,32);
  a3 += __shfl_xor(a3,32); cs += __shfl_xor(cs,32);
  if (sub == 0){
    float iv = 1.f/(cs + 1.f);
    f32x4 wv = {a0*iv, a1*iv, a2*iv, a3*iv};
    *reinterpret_cast<f32x4*>(&agg[(size_t)wid*D_ + ch*4]) = wv;
    if (ch == 0) inv[wid] = iv;
  }
}

// ---- per-node Y GEMM: Ybuf[n][0:64]=W_row@[agg|x0]+b, [64:128]=W_col@[agg|x0] ----
__global__ __launch_bounds__(256) void k_ynode(
    const float* __restrict__ agg, const float* __restrict__ x0b,
    const unsigned short* __restrict__ Wn,
    const float* __restrict__ bias, float* __restrict__ Ybuf, int Nn)
{
  __shared__ __align__(16) short tile[32*104];
  int tid = threadIdx.x;
  int n0 = blockIdx.x*32;
  if (tid < 128){
    int e = tid >> 2, w = tid & 3;
    *reinterpret_cast<short8*>(&tile[e*104 + 72 + w*8]) = short8{0,0,0,0,0,0,0,0};
  }
  const f32x4* agg4 = reinterpret_cast<const f32x4*>(agg);
  const f32x4* x0b4 = reinterpret_cast<const f32x4*>(x0b);
  for (int s = tid; s < 32*18; s += 256){
    int e = s/18, q = s - e*18;
    f32x4 v = {0.f,0.f,0.f,0.f};
    if (n0 + e < Nn){
      if (q < 16) v = agg4[(size_t)(n0+e)*16 + q];
      else        v = x0b4[(size_t)(n0+e)*2 + (q-16)];
    }
    u32x2 pk;
    pk.x = f2bf(v.x) | (f2bf(v.y) << 16);
    pk.y = f2bf(v.z) | (f2bf(v.w) << 16);
    *reinterpret_cast<u32x2*>(&tile[e*104 + q*4]) = pk;
  }
  __syncthreads();
  int lane = tid & 63, wv = tid >> 6;
  int r16 = lane & 15, kg = lane >> 4;
  const short8* W8 = reinterpret_cast<const short8*>(Wn);
  f32x4 acc[2][2] = {};
  #pragma unroll
  for (int kc = 0; kc < 3; ++kc){
    short8 a0 = *reinterpret_cast<const short8*>(&tile[r16*104 + kc*32 + kg*8]);
    short8 a1 = *reinterpret_cast<const short8*>(&tile[(16+r16)*104 + kc*32 + kg*8]);
    #pragma unroll
    for (int t = 0; t < 2; ++t){
      int nt = wv*2 + t;
      short8 wf = W8[(nt*3 + kc)*64 + lane];
      acc[0][t] = __builtin_amdgcn_mfma_f32_16x16x32_bf16(a0, wf, acc[0][t], 0,0,0);
      acc[1][t] = __builtin_amdgcn_mfma_f32_16x16x32_bf16(a1, wf, acc[1][t], 0,0,0);
    }
  }
  #pragma unroll
  for (int t = 0; t < 2; ++t){
    int nt = wv*2 + t;
    int c = nt*16 + r16;
    float b = (nt < 4) ? bias[c] : 0.f;
    #pragma unroll
    for (int m = 0; m < 2; ++m)
      #pragma unroll
      for (int j = 0; j < 4; ++j){
        int node = n0 + m*16 + kg*4 + j;
        if (node < Nn) Ybuf[(size_t)node*128 + c] = acc[m][t][j] + b;
      }
  }
}

// ---- edge GEMM (CSR order) with fused segmented-reduction aggregation ----
template<int FIRST, int FOUT>
__global__ __launch_bounds__(256) void k_gemm(
    const unsigned short* __restrict__ ea_bf, const unsigned short* __restrict__ emb_bf,
    const float* __restrict__ Ybuf,
    unsigned short* __restrict__ ea_out_bf, float* __restrict__ ea_out_f32,
    float* __restrict__ agg,
    const int4* __restrict__ e4, const float* __restrict__ inv,
    const unsigned short* __restrict__ Wea, int E)
{
  __shared__ __align__(16) float stile[EB*68];
  __shared__ int s_row[EB], s_col[EB], s_rel[EB], s_csr[EB];
  __shared__ float s_mask[EB], s_inv[EB];
  int tid = threadIdx.x;
  int e0 = blockIdx.x*EB;
  if (tid < EB){
    int ge = e0 + tid;
    int4 q = {0,0,0,0};
    if (ge < E) q = e4[ge];
    s_row[tid] = q.x;
    s_col[tid] = q.y;
    s_mask[tid]= (ge < E) ? __int_as_float(q.w) : 0.f;
    s_inv[tid] = inv[q.y];
    if (FIRST) s_rel[tid] = q.z & 0xff;
    if (FOUT)  s_csr[tid] = q.z >> 8;
  }
  __syncthreads();
  const f32x4* Yb4 = reinterpret_cast<const f32x4*>(Ybuf);
  f32x4* st4 = reinterpret_cast<f32x4*>(stile);
  #pragma unroll
  for (int h = 0; h < 4; ++h){
    int s = tid + h*256;
    int e = s >> 4, q = s & 15;
    f32x4 a = Yb4[(size_t)s_row[e]*32 + q];
    f32x4 b = Yb4[(size_t)s_col[e]*32 + 16 + q];
    st4[e*17 + q] = a + b;
  }
  int lane = tid & 63, wv = tid >> 6;
  int r16 = lane & 15, kg = lane >> 4;
  const short8* W8 = reinterpret_cast<const short8*>(Wea);
  short8 wf[4][2];
  #pragma unroll
  for (int nt = 0; nt < 4; ++nt)
    #pragma unroll
    for (int kc = 0; kc < 2; ++kc)
      wf[nt][kc] = W8[(nt*2 + kc)*64 + lane];
  f32x4 acc[4] = {};
  #pragma unroll
  for (int kc = 0; kc < 2; ++kc){
    short8 a;
    if (FIRST){
      a = *reinterpret_cast<const short8*>(&emb_bf[(size_t)s_rel[wv*16 + r16]*D_ + kc*32 + kg*8]);
    } else {
      int eA = e0 + wv*16 + r16; if (eA >= E) eA = E-1;
      a = *reinterpret_cast<const short8*>(&ea_bf[(size_t)eA*D_ + kc*32 + kg*8]);
    }
    #pragma unroll
    for (int nt = 0; nt < 4; ++nt)
      acc[nt] = __builtin_amdgcn_mfma_f32_16x16x32_bf16(a, wf[nt][kc], acc[nt], 0,0,0);
  }
  __syncthreads();   // stile Y staging complete before reads
  float v[4][4];
  #pragma unroll
  for (int nt = 0; nt < 4; ++nt)
    #pragma unroll
    for (int j = 0; j < 4; ++j){
      int et = wv*16 + kg*4 + j;           // C/D: row=(lane>>4)*4+j, col=lane&15
      float x = acc[nt][j] + stile[et*68 + nt*16 + r16];
      v[nt][j] = x > 0.f ? x : 0.f;
    }
  __syncthreads();
  if (FOUT == 0){
    unsigned short* ob = reinterpret_cast<unsigned short*>(stile);  // bf16 [64][72]
    #pragma unroll
    for (int nt = 0; nt < 4; ++nt)
      #pragma unroll
      for (int j = 0; j < 4; ++j)
        ob[(wv*16 + kg*4 + j)*72 + nt*16 + r16] = (unsigned short)f2bf(v[nt][j]);
    __syncthreads();
    #pragma unroll
    for (int h = 0; h < 2; ++h){
      int s = tid + h*256;
      int e = s >> 3, w = s & 7;
      int ge = e0 + e;
      if (ge < E)
        *reinterpret_cast<short8*>(&ea_out_bf[(size_t)ge*D_ + w*8]) =
          *reinterpret_cast<const short8*>(&ob[e*72 + w*8]);
    }
    {
      int c = tid & 63, g = tid >> 6;
      int base = g*16;
      int cur = s_col[base]; float civ = s_inv[base]; float run = 0.f;
      #pragma unroll
      for (int e = base; e < base+16; ++e){
        int col = s_col[e];
        if (col != cur){
          atomicAdd(&agg[(size_t)cur*D_ + c], run*civ);
          run = 0.f; cur = col; civ = s_inv[e];
        }
        float val = __uint_as_float((uint32_t)ob[e*72 + c] << 16);
        run += val * s_mask[e];
      }
      atomicAdd(&agg[(size_t)cur*D_ + c], run*civ);
    }
  } else {
    #pragma unroll
    for (int nt = 0; nt < 4; ++nt)
      #pragma unroll
      for (int j = 0; j < 4; ++j)
        stile[(wv*16 + kg*4 + j)*68 + nt*16 + r16] = v[nt][j];
    __syncthreads();
    f32x4* out4 = reinterpret_cast<f32x4*>(ea_out_f32);
    #pragma unroll
    for (int h = 0; h < 4; ++h){
      int s = tid + h*256;
      int e = s >> 4, q = s & 15;
      int ge = e0 + e;
      if (ge < E) out4[(size_t)s_csr[e]*16 + q] = st4[e*17 + q];
    }
    {
      int c = tid & 63, g = tid >> 6;
      int base = g*16;
      int cur = s_col[base]; float civ = s_inv[base]; float run = 0.f;
      #pragma unroll
      for (int e = base; e < base+16; ++e){
        int col = s_col[e];
        if (col != cur){
          atomicAdd(&agg[(size_t)cur*D_ + c], run*civ);
          run = 0.f; cur = col; civ = s_inv[e];
        }
        run += stile[e*68 + c] * s_mask[e];
      }
      atomicAdd(&agg[(size_t)cur*D_ + c], run*civ);
    }
  }
}

__global__ void k_pool(const float* __restrict__ nrep_out, const int* __restrict__ head,
                       const int* __restrict__ counts, float* __restrict__ gout, int B){
  __shared__ float s[4][64];
  int g = blockIdx.x;
  int lane = threadIdx.x & 63, sub = threadIdx.x >> 6;
  int h = head[g]; int n = counts[g];
  float m = -3.402823466e38f;
  for (int i = sub; i < n; i += 4)
    m = fmaxf(m, nrep_out[(size_t)(h+i)*D_ + lane]);
  s[sub][lane] = m;
  __syncthreads();
  if (sub == 0){
    m = fmaxf(fmaxf(s[0][lane], s[1][lane]), fmaxf(s[2][lane], s[3][lane]));
    gout[(size_t)g*192 + lane]       = m;
    gout[(size_t)g*192 + 64  + lane] = nrep_out[(size_t)h*D_ + lane];
    gout[(size_t)g*192 + 128 + lane] = nrep_out[(size_t)(h+1)*D_ + lane];
  }
}

extern "C" void kernel_launch(void* const* d_in, const int* in_sizes, int n_in,
                              void* d_out, int out_size, void* d_ws, size_t ws_size,
                              hipStream_t stream)
{
  const float* x    = (const float*)d_in[0];
  const int*   eidx = (const int*)d_in[1];
  const int*   erel = (const int*)d_in[2];
  const int*   batch= (const int*)d_in[3];
  const float* mask = (const float*)d_in[4];
  const float* emb  = (const float*)d_in[5];
  const float* W0   = (const float*)d_in[6];
  const float* b0   = (const float*)d_in[7];
  const float* W1   = (const float*)d_in[8];
  const float* b1   = (const float*)d_in[9];
  const float* W2   = (const float*)d_in[10];
  const float* b2   = (const float*)d_in[11];

  int N = in_sizes[0] / NODE_DIM_;
  int E = in_sizes[2];
  int B = (int)(((long long)out_size - (long long)N*D_ - (long long)E*D_) / 192);

  float* out_ge   = (float*)d_out;                 // B*192
  float* out_nrep = out_ge + (size_t)B*192;        // N*64  (atomic target of layer-2 gemm)
  float* out_ea   = out_nrep + (size_t)N*D_;       // E*64  (f32, original edge order)

  char* w = (char*)d_ws;
  auto alloc = [&](size_t bytes)->char*{ char* p = w; w += (bytes + 255) & ~(size_t)255; return p; };
  unsigned short* ea_p = (unsigned short*)alloc((size_t)E*D_*2);    // 102.4 MB (CSR order)
  float* Ybuf   = (float*)alloc((size_t)N*128*4);                   // 25.6 MB
  float* aggA   = (float*)alloc((size_t)N*D_*4);                    // agg0 output (fully written)
  float* invb   = (float*)alloc((size_t)N*4);
  // ---- contiguous zero-init region ----
  float* aggB   = (float*)alloc((size_t)N*D_*4);                    // gemm0 atomic target
  float* aggC   = (float*)alloc((size_t)N*D_*4);                    // gemm1 atomic target
  int*   cnt_i  = (int*)  alloc((size_t)N*4);
  int*   counts = (int*)  alloc((size_t)B*4);
  float* x0b    = (float*)alloc((size_t)N*8*4);
  size_t zspan  = (size_t)((char*)x0b + (size_t)N*8*4 - (char*)aggB);
  // -------------------------------------
  int*   off    = (int*)  alloc((size_t)(N+1)*4);
  int*   fpos   = (int*)  alloc((size_t)N*4);
  int4*  e4     = (int4*) alloc((size_t)E*16);                      // 12.8 MB
  int*   head   = (int*)  alloc((size_t)B*4);
  unsigned short* Wea = (unsigned short*)alloc((size_t)3*WEA_PER_LAYER*2);
  unsigned short* Wn  = (unsigned short*)alloc((size_t)3*WN_PER_LAYER*2);
  unsigned short* emb_bf = (unsigned short*)alloc((size_t)200*D_*2 + 256);

  hipMemsetAsync(aggB, 0, zspan, stream);
  hipMemsetAsync(out_nrep, 0, (size_t)N*D_*4, stream);

  const int* erow = eidx;
  const int* ecol = eidx + E;

  k_counts <<<(E+255)/256, 256, 0, stream>>>(batch, ecol, counts, cnt_i, N, E);
  k_scans  <<<1, 1024, 0, stream>>>(cnt_i, off, N, counts, head, B, x, x0b);
  hipMemcpyAsync(fpos, off, (size_t)N*4, hipMemcpyDeviceToDevice, stream);
  k_fill   <<<(E+255)/256, 256, 0, stream>>>(erow, ecol, erel, mask, fpos, e4, E);
  k_pack   <<<(3*(WEA_PER_LAYER+WN_PER_LAYER)+200*D_+255)/256, 256, 0, stream>>>(
             W0, W1, W2, emb, Wea, Wn, emb_bf);

  int nblk_g = (E + EB - 1) / EB;
  int nblk_a = (N + 3) / 4;
  int nblk_y = (N + 31) / 32;

  // layer 0
  k_agg0_inv<<<nblk_a, 256, 0, stream>>>(emb, e4, off, aggA, invb, N);
  k_ynode<<<nblk_y, 256, 0, stream>>>(aggA, x0b, Wn, b0, Ybuf, N);
  k_gemm<1,0><<<nblk_g, 256, 0, stream>>>(ea_p, emb_bf, Ybuf, ea_p, out_ea, aggB,
                                          e4, invb, Wea, E);
  // layer 1
  k_ynode<<<nblk_y, 256, 0, stream>>>(aggB, x0b, Wn + WN_PER_LAYER, b1, Ybuf, N);
  k_gemm<0,0><<<nblk_g, 256, 0, stream>>>(ea_p, emb_bf, Ybuf, ea_p, out_ea, aggC,
                                          e4, invb, Wea + WEA_PER_LAYER, E);
  // layer 2 (f32 scatter to d_out + atomics into out_nrep)
  k_ynode<<<nblk_y, 256, 0, stream>>>(aggC, x0b, Wn + 2*WN_PER_LAYER, b2, Ybuf, N);
  k_gemm<0,1><<<nblk_g, 256, 0, stream>>>(ea_p, emb_bf, Ybuf, ea_p, out_ea, out_nrep,
                                          e4, invb, Wea + 2*WEA_PER_LAYER, E);

  k_pool<<<B, 256, 0, stream>>>(out_nrep, head, counts, out_ge, B);
}

// Round 8
// 719.254 us; speedup vs baseline: 2.3727x; 1.0200x over previous
//
#include <hip/hip_runtime.h>
#include <stdint.h>

typedef __attribute__((ext_vector_type(8))) short short8;
typedef __attribute__((ext_vector_type(4))) float f32x4;
typedef __attribute__((ext_vector_type(2))) unsigned int u32x2;

#define D_ 64
#define NODE_DIM_ 6
#define INF_ 204          // IN_FEAT = 3*64 + 2*6
#define EB 64             // edges per GEMM block
#define WEA_PER_LAYER 4096    // 4nt*2kc*64lane*8
#define WN_PER_LAYER 12288    // 8nt*3kc*64lane*8

__device__ __forceinline__ unsigned int f2bf(float f){
  uint32_t u = __float_as_uint(f);
  u += 0x7fffu + ((u >> 16) & 1u);   // RNE (finite values only)
  return u >> 16;
}

// merged: batch-count (N) + col-count (E)
__global__ void k_counts(const int* __restrict__ batch, const int* __restrict__ col,
                         int* __restrict__ counts, int* __restrict__ cnt, int N, int E){
  int i = blockIdx.x*256 + threadIdx.x;
  if (i < E) atomicAdd(&cnt[col[i]], 1);
  if (i < N) atomicAdd(&counts[batch[i]], 1);
}

// merged: CSR offset scan (N+1, also seeds fpos) + head-index scan (B) + x0 gather
__global__ void k_scans(const int* __restrict__ cnt, int* __restrict__ off,
                        int* __restrict__ fpos, int Nn,
                        const int* __restrict__ counts, int* __restrict__ head, int B,
                        const float* __restrict__ x, float* __restrict__ x0b){
  __shared__ int s[1024];
  int t = threadIdx.x;
  const int CH = (Nn + 1024) / 1024;
  int base = t*CH;
  int sum = 0;
  for (int i = 0; i < CH; ++i){ int idx = base+i; if (idx < Nn) sum += cnt[idx]; }
  s[t] = sum;
  __syncthreads();
  for (int o = 1; o < 1024; o <<= 1){
    int u = (t >= o) ? s[t-o] : 0;
    __syncthreads();
    s[t] += u;
    __syncthreads();
  }
  int run = (t == 0) ? 0 : s[t-1];
  for (int i = 0; i < CH; ++i){
    int idx = base+i;
    if (idx <= Nn){
      off[idx] = run;
      if (idx < Nn){ fpos[idx] = run; run += cnt[idx]; }
    }
  }
  __syncthreads();
  // phase 2: head indices
  int v = (t < B) ? counts[t] : 0;
  s[t] = v;
  __syncthreads();
  for (int o = 1; o < 1024; o <<= 1){
    int u = (t >= o) ? s[t-o] : 0;
    __syncthreads();
    s[t] += u;
    __syncthreads();
  }
  if (t < B) head[t] = s[t] - v;
  __syncthreads();
  // phase 3: x0 gather (head/tail node features -> x0b[node][0:6])
  for (int idx = t; idx < B*2*NODE_DIM_; idx += 1024){
    int g = idx / (2*NODE_DIM_);
    int j = idx % (2*NODE_DIM_);
    int node = (s[g] - counts[g]) + j / NODE_DIM_;
    int c = j % NODE_DIM_;
    x0b[(size_t)node*8 + c] = x[node*NODE_DIM_ + c];
  }
}

// scatter edge data into CSR order: ONE 16B store per edge
// e4[pos] = {row, col, (orig_e<<8)|rel, mask_bits}
__global__ void k_fill(const int* __restrict__ row, const int* __restrict__ col,
                       const int* __restrict__ rel, const float* __restrict__ mask,
                       int* __restrict__ fpos, int4* __restrict__ e4, int E){
  int e = blockIdx.x*256 + threadIdx.x;
  if (e >= E) return;
  int c = col[e];
  int pos = atomicAdd(&fpos[c], 1);   // fpos pre-loaded with off[]
  e4[pos] = make_int4(row[e], c, (e << 8) | rel[e], __float_as_int(mask[e]));
}

// pack W_ea (c,140+k), W_node (Yrow: c,k | Ycol: c-64,70+k), and emb -> bf16
__global__ void k_pack(const float* __restrict__ W0, const float* __restrict__ W1,
                       const float* __restrict__ W2, const float* __restrict__ emb,
                       unsigned short* __restrict__ Wea, unsigned short* __restrict__ Wn,
                       unsigned short* __restrict__ emb_bf){
  int idx = blockIdx.x*256 + threadIdx.x;
  if (idx < 3*WEA_PER_LAYER){
    int l = idx / WEA_PER_LAYER;
    int rem = idx % WEA_PER_LAYER;
    const float* W = (l==0) ? W0 : ((l==1) ? W1 : W2);
    int i = rem & 7, s = rem >> 3;
    int lane = s & 63, t = s >> 6;          // t = nt*2 + kc
    int kc = t & 1, nt = t >> 1;
    int n = lane & 15, kg = lane >> 4;
    int k = kc*32 + kg*8 + i;               // 0..63
    int c = nt*16 + n;                      // 0..63
    Wea[idx] = (unsigned short)f2bf(W[c*INF_ + 140 + k]);
    return;
  }
  int idx2 = idx - 3*WEA_PER_LAYER;
  if (idx2 < 3*WN_PER_LAYER){
    int l = idx2 / WN_PER_LAYER;
    int rem = idx2 % WN_PER_LAYER;
    const float* W = (l==0) ? W0 : ((l==1) ? W1 : W2);
    int i = rem & 7, s = rem >> 3;
    int lane = s & 63, t = s >> 6;            // t = nt*3 + kc
    int kc = t % 3, nt = t / 3;               // nt 0..7
    int n = lane & 15, kg = lane >> 4;
    int k = kc*32 + kg*8 + i;                 // 0..95
    int c = nt*16 + n;                        // 0..127
    float v = 0.f;
    if (k < 70) v = (nt < 4) ? W[c*INF_ + k] : W[(c-64)*INF_ + 70 + k];
    Wn[idx2] = (unsigned short)f2bf(v);
    return;
  }
  int idx3 = idx2 - 3*WN_PER_LAYER;
  if (idx3 < 200*D_) emb_bf[idx3] = (unsigned short)f2bf(emb[idx3]);
}

// layer-0 aggregation: divided sums -> agg (stride 64), and inv[n]=1/(cs+1)
__global__ __launch_bounds__(256) void k_agg0_inv(
    const float* __restrict__ emb, const int4* __restrict__ e4,
    const int* __restrict__ off, float* __restrict__ agg,
    float* __restrict__ inv, int Nn)
{
  int wid = (blockIdx.x*256 + threadIdx.x) >> 6;
  if (wid >= Nn) return;
  int lane = threadIdx.x & 63;
  int sub = lane >> 4, ch = lane & 15;
  int s = off[wid], t = off[wid+1];
  float a0=0.f,a1=0.f,a2=0.f,a3=0.f, cs=0.f;
  for (int i = s; i < t; i += 4){
    int ii = i + sub;
    float mv = 0.f; int r = 0;
    if (ii < t){ int4 q = e4[ii]; r = q.z & 0xff; mv = __int_as_float(q.w); }
    f32x4 v = *reinterpret_cast<const f32x4*>(&emb[r*D_ + ch*4]);
    a0 += v.x*mv; a1 += v.y*mv; a2 += v.z*mv; a3 += v.w*mv;
    cs += mv;
  }
  a0 += __shfl_xor(a0,16); a1 += __shfl_xor(a1,16); a2 += __shfl_xor(a2,16);
  a3 += __shfl_xor(a3,16); cs += __shfl_xor(cs,16);
  a0 += __shfl_xor(a0,32); a1 += __shfl_xor(a1,32); a2 += __shfl_xor(a2,32);
  a3 += __shfl_xor(a3,32); cs += __shfl_xor(cs,32);
  if (sub == 0){
    float iv = 1.f/(cs + 1.f);
    f32x4 wv = {a0*iv, a1*iv, a2*iv, a3*iv};
    *reinterpret_cast<f32x4*>(&agg[(size_t)wid*D_ + ch*4]) = wv;
    if (ch == 0) inv[wid] = iv;
  }
}

// ---- per-node Y GEMM: Ybf[n][0:64]=bf16(W_row@[agg|x0]+b), [64:128]=bf16(W_col@[agg|x0]) ----
__global__ __launch_bounds__(256) void k_ynode(
    const float* __restrict__ agg, const float* __restrict__ x0b,
    const unsigned short* __restrict__ Wn,
    const float* __restrict__ bias, unsigned short* __restrict__ Ybf, int Nn)
{
  __shared__ __align__(16) short tile[32*104];
  int tid = threadIdx.x;
  int n0 = blockIdx.x*32;
  if (tid < 128){
    int e = tid >> 2, w = tid & 3;
    *reinterpret_cast<short8*>(&tile[e*104 + 72 + w*8]) = short8{0,0,0,0,0,0,0,0};
  }
  const f32x4* agg4 = reinterpret_cast<const f32x4*>(agg);
  const f32x4* x0b4 = reinterpret_cast<const f32x4*>(x0b);
  for (int s = tid; s < 32*18; s += 256){
    int e = s/18, q = s - e*18;
    f32x4 v = {0.f,0.f,0.f,0.f};
    if (n0 + e < Nn){
      if (q < 16) v = agg4[(size_t)(n0+e)*16 + q];
      else        v = x0b4[(size_t)(n0+e)*2 + (q-16)];
    }
    u32x2 pk;
    pk.x = f2bf(v.x) | (f2bf(v.y) << 16);
    pk.y = f2bf(v.z) | (f2bf(v.w) << 16);
    *reinterpret_cast<u32x2*>(&tile[e*104 + q*4]) = pk;
  }
  __syncthreads();
  int lane = tid & 63, wv = tid >> 6;
  int r16 = lane & 15, kg = lane >> 4;
  const short8* W8 = reinterpret_cast<const short8*>(Wn);
  f32x4 acc[2][2] = {};
  #pragma unroll
  for (int kc = 0; kc < 3; ++kc){
    short8 a0 = *reinterpret_cast<const short8*>(&tile[r16*104 + kc*32 + kg*8]);
    short8 a1 = *reinterpret_cast<const short8*>(&tile[(16+r16)*104 + kc*32 + kg*8]);
    #pragma unroll
    for (int t = 0; t < 2; ++t){
      int nt = wv*2 + t;
      short8 wf = W8[(nt*3 + kc)*64 + lane];
      acc[0][t] = __builtin_amdgcn_mfma_f32_16x16x32_bf16(a0, wf, acc[0][t], 0,0,0);
      acc[1][t] = __builtin_amdgcn_mfma_f32_16x16x32_bf16(a1, wf, acc[1][t], 0,0,0);
    }
  }
  #pragma unroll
  for (int t = 0; t < 2; ++t){
    int nt = wv*2 + t;
    int c = nt*16 + r16;
    float b = (nt < 4) ? bias[c] : 0.f;
    #pragma unroll
    for (int m = 0; m < 2; ++m)
      #pragma unroll
      for (int j = 0; j < 4; ++j){
        int node = n0 + m*16 + kg*4 + j;
        if (node < Nn) Ybf[(size_t)node*128 + c] = (unsigned short)f2bf(acc[m][t][j] + b);
      }
  }
}

// ---- edge GEMM (CSR order) with fused segmented-reduction aggregation ----
// Y gathers from bf16 Ybf: per edge 128B (row half) + 128B (col half)
template<int FIRST, int FOUT>
__global__ __launch_bounds__(256) void k_gemm(
    const unsigned short* __restrict__ ea_bf, const unsigned short* __restrict__ emb_bf,
    const unsigned short* __restrict__ Ybf,
    unsigned short* __restrict__ ea_out_bf, float* __restrict__ ea_out_f32,
    float* __restrict__ agg,
    const int4* __restrict__ e4, const float* __restrict__ inv,
    const unsigned short* __restrict__ Wea, int E)
{
  __shared__ __align__(16) float stile[EB*68];
  __shared__ int s_row[EB], s_col[EB], s_rel[EB], s_csr[EB];
  __shared__ float s_mask[EB], s_inv[EB];
  int tid = threadIdx.x;
  int e0 = blockIdx.x*EB;
  if (tid < EB){
    int ge = e0 + tid;
    int4 q = {0,0,0,0};
    if (ge < E) q = e4[ge];
    s_row[tid] = q.x;
    s_col[tid] = q.y;
    s_mask[tid]= (ge < E) ? __int_as_float(q.w) : 0.f;
    s_inv[tid] = inv[q.y];
    if (FIRST) s_rel[tid] = q.z & 0xff;
    if (FOUT)  s_csr[tid] = q.z >> 8;
  }
  __syncthreads();
  const unsigned int* Yb = reinterpret_cast<const unsigned int*>(Ybf);  // 64 u32 per node
  f32x4* st4 = reinterpret_cast<f32x4*>(stile);
  #pragma unroll
  for (int h = 0; h < 4; ++h){
    int s = tid + h*256;
    int e = s >> 4, q = s & 15;
    u32x2 ra = *reinterpret_cast<const u32x2*>(Yb + (size_t)s_row[e]*64 + q*2);
    u32x2 rb = *reinterpret_cast<const u32x2*>(Yb + (size_t)s_col[e]*64 + 32 + q*2);
    f32x4 v;
    v.x = __uint_as_float(ra.x << 16)         + __uint_as_float(rb.x << 16);
    v.y = __uint_as_float(ra.x & 0xffff0000u) + __uint_as_float(rb.x & 0xffff0000u);
    v.z = __uint_as_float(ra.y << 16)         + __uint_as_float(rb.y << 16);
    v.w = __uint_as_float(ra.y & 0xffff0000u) + __uint_as_float(rb.y & 0xffff0000u);
    st4[e*17 + q] = v;
  }
  int lane = tid & 63, wv = tid >> 6;
  int r16 = lane & 15, kg = lane >> 4;
  const short8* W8 = reinterpret_cast<const short8*>(Wea);
  short8 wf[4][2];
  #pragma unroll
  for (int nt = 0; nt < 4; ++nt)
    #pragma unroll
    for (int kc = 0; kc < 2; ++kc)
      wf[nt][kc] = W8[(nt*2 + kc)*64 + lane];
  f32x4 acc[4] = {};
  #pragma unroll
  for (int kc = 0; kc < 2; ++kc){
    short8 a;
    if (FIRST){
      a = *reinterpret_cast<const short8*>(&emb_bf[(size_t)s_rel[wv*16 + r16]*D_ + kc*32 + kg*8]);
    } else {
      int eA = e0 + wv*16 + r16; if (eA >= E) eA = E-1;
      a = *reinterpret_cast<const short8*>(&ea_bf[(size_t)eA*D_ + kc*32 + kg*8]);
    }
    #pragma unroll
    for (int nt = 0; nt < 4; ++nt)
      acc[nt] = __builtin_amdgcn_mfma_f32_16x16x32_bf16(a, wf[nt][kc], acc[nt], 0,0,0);
  }
  __syncthreads();   // stile Y staging complete before reads
  float v[4][4];
  #pragma unroll
  for (int nt = 0; nt < 4; ++nt)
    #pragma unroll
    for (int j = 0; j < 4; ++j){
      int et = wv*16 + kg*4 + j;           // C/D: row=(lane>>4)*4+j, col=lane&15
      float x = acc[nt][j] + stile[et*68 + nt*16 + r16];
      v[nt][j] = x > 0.f ? x : 0.f;
    }
  __syncthreads();
  if (FOUT == 0){
    unsigned short* ob = reinterpret_cast<unsigned short*>(stile);  // bf16 [64][72]
    #pragma unroll
    for (int nt = 0; nt < 4; ++nt)
      #pragma unroll
      for (int j = 0; j < 4; ++j)
        ob[(wv*16 + kg*4 + j)*72 + nt*16 + r16] = (unsigned short)f2bf(v[nt][j]);
    __syncthreads();
    #pragma unroll
    for (int h = 0; h < 2; ++h){
      int s = tid + h*256;
      int e = s >> 3, w = s & 7;
      int ge = e0 + e;
      if (ge < E)
        *reinterpret_cast<short8*>(&ea_out_bf[(size_t)ge*D_ + w*8]) =
          *reinterpret_cast<const short8*>(&ob[e*72 + w*8]);
    }
    {
      int c = tid & 63, g = tid >> 6;
      int base = g*16;
      int cur = s_col[base]; float civ = s_inv[base]; float run = 0.f;
      #pragma unroll
      for (int e = base; e < base+16; ++e){
        int col = s_col[e];
        if (col != cur){
          atomicAdd(&agg[(size_t)cur*D_ + c], run*civ);
          run = 0.f; cur = col; civ = s_inv[e];
        }
        float val = __uint_as_float((uint32_t)ob[e*72 + c] << 16);
        run += val * s_mask[e];
      }
      atomicAdd(&agg[(size_t)cur*D_ + c], run*civ);
    }
  } else {
    #pragma unroll
    for (int nt = 0; nt < 4; ++nt)
      #pragma unroll
      for (int j = 0; j < 4; ++j)
        stile[(wv*16 + kg*4 + j)*68 + nt*16 + r16] = v[nt][j];
    __syncthreads();
    f32x4* out4 = reinterpret_cast<f32x4*>(ea_out_f32);
    #pragma unroll
    for (int h = 0; h < 4; ++h){
      int s = tid + h*256;
      int e = s >> 4, q = s & 15;
      int ge = e0 + e;
      if (ge < E) out4[(size_t)s_csr[e]*16 + q] = st4[e*17 + q];
    }
    {
      int c = tid & 63, g = tid >> 6;
      int base = g*16;
      int cur = s_col[base]; float civ = s_inv[base]; float run = 0.f;
      #pragma unroll
      for (int e = base; e < base+16; ++e){
        int col = s_col[e];
        if (col != cur){
          atomicAdd(&agg[(size_t)cur*D_ + c], run*civ);
          run = 0.f; cur = col; civ = s_inv[e];
        }
        run += stile[e*68 + c] * s_mask[e];
      }
      atomicAdd(&agg[(size_t)cur*D_ + c], run*civ);
    }
  }
}

__global__ void k_pool(const float* __restrict__ nrep_out, const int* __restrict__ head,
                       const int* __restrict__ counts, float* __restrict__ gout, int B){
  __shared__ float s[4][64];
  int g = blockIdx.x;
  int lane = threadIdx.x & 63, sub = threadIdx.x >> 6;
  int h = head[g]; int n = counts[g];
  float m = -3.402823466e38f;
  for (int i = sub; i < n; i += 4)
    m = fmaxf(m, nrep_out[(size_t)(h+i)*D_ + lane]);
  s[sub][lane] = m;
  __syncthreads();
  if (sub == 0){
    m = fmaxf(fmaxf(s[0][lane], s[1][lane]), fmaxf(s[2][lane], s[3][lane]));
    gout[(size_t)g*192 + lane]       = m;
    gout[(size_t)g*192 + 64  + lane] = nrep_out[(size_t)h*D_ + lane];
    gout[(size_t)g*192 + 128 + lane] = nrep_out[(size_t)(h+1)*D_ + lane];
  }
}

extern "C" void kernel_launch(void* const* d_in, const int* in_sizes, int n_in,
                              void* d_out, int out_size, void* d_ws, size_t ws_size,
                              hipStream_t stream)
{
  const float* x    = (const float*)d_in[0];
  const int*   eidx = (const int*)d_in[1];
  const int*   erel = (const int*)d_in[2];
  const int*   batch= (const int*)d_in[3];
  const float* mask = (const float*)d_in[4];
  const float* emb  = (const float*)d_in[5];
  const float* W0   = (const float*)d_in[6];
  const float* b0   = (const float*)d_in[7];
  const float* W1   = (const float*)d_in[8];
  const float* b1   = (const float*)d_in[9];
  const float* W2   = (const float*)d_in[10];
  const float* b2   = (const float*)d_in[11];

  int N = in_sizes[0] / NODE_DIM_;
  int E = in_sizes[2];
  int B = (int)(((long long)out_size - (long long)N*D_ - (long long)E*D_) / 192);

  float* out_ge   = (float*)d_out;                 // B*192
  float* out_nrep = out_ge + (size_t)B*192;        // N*64  (atomic target of layer-2 gemm)
  float* out_ea   = out_nrep + (size_t)N*D_;       // E*64  (f32, original edge order)

  char* w = (char*)d_ws;
  auto alloc = [&](size_t bytes)->char*{ char* p = w; w += (bytes + 255) & ~(size_t)255; return p; };
  unsigned short* ea_p = (unsigned short*)alloc((size_t)E*D_*2);    // 102.4 MB (CSR order)
  unsigned short* Ybf  = (unsigned short*)alloc((size_t)N*128*2);   // 12.8 MB (bf16 Y)
  float* aggA   = (float*)alloc((size_t)N*D_*4);                    // agg0 output (fully written)
  float* invb   = (float*)alloc((size_t)N*4);
  // ---- contiguous zero-init region ----
  float* aggB   = (float*)alloc((size_t)N*D_*4);                    // gemm0 atomic target
  float* aggC   = (float*)alloc((size_t)N*D_*4);                    // gemm1 atomic target
  int*   cnt_i  = (int*)  alloc((size_t)N*4);
  int*   counts = (int*)  alloc((size_t)B*4);
  float* x0b    = (float*)alloc((size_t)N*8*4);
  size_t zspan  = (size_t)((char*)x0b + (size_t)N*8*4 - (char*)aggB);
  // -------------------------------------
  int*   off    = (int*)  alloc((size_t)(N+1)*4);
  int*   fpos   = (int*)  alloc((size_t)N*4);
  int4*  e4     = (int4*) alloc((size_t)E*16);                      // 12.8 MB
  int*   head   = (int*)  alloc((size_t)B*4);
  unsigned short* Wea = (unsigned short*)alloc((size_t)3*WEA_PER_LAYER*2);
  unsigned short* Wn  = (unsigned short*)alloc((size_t)3*WN_PER_LAYER*2);
  unsigned short* emb_bf = (unsigned short*)alloc((size_t)200*D_*2 + 256);

  hipMemsetAsync(aggB, 0, zspan, stream);
  hipMemsetAsync(out_nrep, 0, (size_t)N*D_*4, stream);

  const int* erow = eidx;
  const int* ecol = eidx + E;

  k_counts <<<(E+255)/256, 256, 0, stream>>>(batch, ecol, counts, cnt_i, N, E);
  k_scans  <<<1, 1024, 0, stream>>>(cnt_i, off, fpos, N, counts, head, B, x, x0b);
  k_fill   <<<(E+255)/256, 256, 0, stream>>>(erow, ecol, erel, mask, fpos, e4, E);
  k_pack   <<<(3*(WEA_PER_LAYER+WN_PER_LAYER)+200*D_+255)/256, 256, 0, stream>>>(
             W0, W1, W2, emb, Wea, Wn, emb_bf);

  int nblk_g = (E + EB - 1) / EB;
  int nblk_a = (N + 3) / 4;
  int nblk_y = (N + 31) / 32;

  // layer 0
  k_agg0_inv<<<nblk_a, 256, 0, stream>>>(emb, e4, off, aggA, invb, N);
  k_ynode<<<nblk_y, 256, 0, stream>>>(aggA, x0b, Wn, b0, Ybf, N);
  k_gemm<1,0><<<nblk_g, 256, 0, stream>>>(ea_p, emb_bf, Ybf, ea_p, out_ea, aggB,
                                          e4, invb, Wea, E);
  // layer 1
  k_ynode<<<nblk_y, 256, 0, stream>>>(aggB, x0b, Wn + WN_PER_LAYER, b1, Ybf, N);
  k_gemm<0,0><<<nblk_g, 256, 0, stream>>>(ea_p, emb_bf, Ybf, ea_p, out_ea, aggC,
                                          e4, invb, Wea + WEA_PER_LAYER, E);
  // layer 2 (f32 scatter to d_out + atomics into out_nrep)
  k_ynode<<<nblk_y, 256, 0, stream>>>(aggC, x0b, Wn + 2*WN_PER_LAYER, b2, Ybf, N);
  k_gemm<0,1><<<nblk_g, 256, 0, stream>>>(ea_p, emb_bf, Ybf, ea_p, out_ea, out_nrep,
                                          e4, invb, Wea + 2*WEA_PER_LAYER, E);

  k_pool<<<B, 256, 0, stream>>>(out_nrep, head, counts, out_ge, B);
}